// Round 1
// baseline (1586.959 us; speedup 1.0000x reference)
//
#include <hip/hip_runtime.h>
#include <hip/hip_bf16.h>
#include <math.h>

namespace {

constexpr int Bc = 2;
constexpr int Sc = 2048;
constexpr int Ec = 1024;
constexpr int Hc = 8;
constexpr int Dc = 128;
constexpr int Mc = Bc * Sc; // 4096

// ---------------------------------------------------------------------------
// Generic tiled f32 GEMM: C[M,E] = A[M,E] * B[E,E], 128x128x16 tile, 256 thr,
// 8x8 per thread. EPI: 0 = none, 1 = silu.
// ---------------------------------------------------------------------------
template<int EPI>
__global__ __launch_bounds__(256) void gemm_kernel(const float* __restrict__ A,
                                                   const float* __restrict__ Bm,
                                                   float* __restrict__ C)
{
    const int t  = threadIdx.x;
    const int ty = t >> 4, tx = t & 15;
    const int r0 = blockIdx.x * 128;
    const int n0 = blockIdx.y * 128;

    __shared__ float As[16][132];
    __shared__ float Bs[16][132];

    float acc[8][8] = {};

    const int ar = t >> 1;          // 0..127
    const int ak = (t & 1) * 8;     // 0 / 8
    const int bk = t >> 4;          // 0..15
    const int bn = (t & 15) * 8;    // 0..120

    const float* Ap = A  + (size_t)(r0 + ar) * Ec + ak;
    const float* Bp = Bm + (size_t)bk * Ec + n0 + bn;

    for (int k0 = 0; k0 < Ec; k0 += 16) {
        float4 a0 = *(const float4*)(Ap + k0);
        float4 a1 = *(const float4*)(Ap + k0 + 4);
        float4 b0 = *(const float4*)(Bp + (size_t)k0 * Ec);
        float4 b1 = *(const float4*)(Bp + (size_t)k0 * Ec + 4);
        As[ak + 0][ar] = a0.x; As[ak + 1][ar] = a0.y;
        As[ak + 2][ar] = a0.z; As[ak + 3][ar] = a0.w;
        As[ak + 4][ar] = a1.x; As[ak + 5][ar] = a1.y;
        As[ak + 6][ar] = a1.z; As[ak + 7][ar] = a1.w;
        *(float4*)&Bs[bk][bn]     = b0;
        *(float4*)&Bs[bk][bn + 4] = b1;
        __syncthreads();
#pragma unroll
        for (int kk = 0; kk < 16; ++kk) {
            float a[8], b[8];
            *(float4*)(a)     = *(const float4*)&As[kk][ty * 8];
            *(float4*)(a + 4) = *(const float4*)&As[kk][ty * 8 + 4];
            *(float4*)(b)     = *(const float4*)&Bs[kk][tx * 8];
            *(float4*)(b + 4) = *(const float4*)&Bs[kk][tx * 8 + 4];
#pragma unroll
            for (int i = 0; i < 8; ++i)
#pragma unroll
                for (int j = 0; j < 8; ++j)
                    acc[i][j] = fmaf(a[i], b[j], acc[i][j]);
        }
        __syncthreads();
    }

#pragma unroll
    for (int i = 0; i < 8; ++i) {
        const int row = r0 + ty * 8 + i;
        float* crow = C + (size_t)row * Ec + n0 + tx * 8;
        float v[8];
#pragma unroll
        for (int j = 0; j < 8; ++j) {
            float x = acc[i][j];
            if (EPI == 1) x = x / (1.f + expf(-x)); // silu
            v[j] = x;
        }
        *(float4*)(crow)     = *(float4*)(v);
        *(float4*)(crow + 4) = *(float4*)(v + 4);
    }
}

// ---------------------------------------------------------------------------
// Projection GEMM: Out[b,h,s,d] = sum_e X[b,s,e] * W[h,e,d], with fused xPos.
// MODE: 0 = none (V), 1 = xpos up (Q), 2 = xpos down (K).
// Tile: 128 rows x 128 cols (= whole head dim), BK=16.
// ---------------------------------------------------------------------------
template<int MODE>
__global__ __launch_bounds__(256) void proj_kernel(const float* __restrict__ X,
                                                   const float* __restrict__ W,
                                                   float* __restrict__ Out)
{
    const int t  = threadIdx.x;
    const int ty = t >> 4, tx = t & 15;
    const int r0 = blockIdx.x * 128;
    const int h  = blockIdx.y;

    __shared__ float As[16][132];
    __shared__ float Bs[16][132];

    float acc[8][8] = {};

    const int ar = t >> 1;
    const int ak = (t & 1) * 8;
    const int bk = t >> 4;
    const int bn = (t & 15) * 8;

    const float* Ap = X + (size_t)(r0 + ar) * Ec + ak;
    const float* Bp = W + ((size_t)h * Ec + bk) * Dc + bn;

    for (int k0 = 0; k0 < Ec; k0 += 16) {
        float4 a0 = *(const float4*)(Ap + k0);
        float4 a1 = *(const float4*)(Ap + k0 + 4);
        float4 b0 = *(const float4*)(Bp + (size_t)k0 * Dc);
        float4 b1 = *(const float4*)(Bp + (size_t)k0 * Dc + 4);
        As[ak + 0][ar] = a0.x; As[ak + 1][ar] = a0.y;
        As[ak + 2][ar] = a0.z; As[ak + 3][ar] = a0.w;
        As[ak + 4][ar] = a1.x; As[ak + 5][ar] = a1.y;
        As[ak + 6][ar] = a1.z; As[ak + 7][ar] = a1.w;
        *(float4*)&Bs[bk][bn]     = b0;
        *(float4*)&Bs[bk][bn + 4] = b1;
        __syncthreads();
#pragma unroll
        for (int kk = 0; kk < 16; ++kk) {
            float a[8], b[8];
            *(float4*)(a)     = *(const float4*)&As[kk][ty * 8];
            *(float4*)(a + 4) = *(const float4*)&As[kk][ty * 8 + 4];
            *(float4*)(b)     = *(const float4*)&Bs[kk][tx * 8];
            *(float4*)(b + 4) = *(const float4*)&Bs[kk][tx * 8 + 4];
#pragma unroll
            for (int i = 0; i < 8; ++i)
#pragma unroll
                for (int j = 0; j < 8; ++j)
                    acc[i][j] = fmaf(a[i], b[j], acc[i][j]);
        }
        __syncthreads();
    }

#pragma unroll
    for (int i = 0; i < 8; ++i) {
        const int row = r0 + ty * 8 + i;
        const int bidx = row / Sc;
        const int s    = row % Sc;
        float* orow = Out + ((size_t)(bidx * Hc + h) * Sc + s) * Dc + tx * 8;
        if (MODE == 0) {
            *(float4*)(orow)     = *(float4*)&acc[i][0];
            *(float4*)(orow + 4) = *(float4*)&acc[i][4];
        } else {
            const float sp = (float)s;
            float v[8];
#pragma unroll
            for (int j2 = 0; j2 < 4; ++j2) {
                const int d  = tx * 8 + 2 * j2;
                const int ip = d >> 1;
                // scale_vec = (d + 0.4*128)/(1.4*128); scale = scale_vec^(s/512)
                const float sv = (2.f * (float)ip + 51.2f) * (1.f / 179.2f);
                float sc = exp2f((sp * (1.f / 512.f)) * log2f(sv));
                if (MODE == 2) sc = 1.f / sc;
                // inv_freq = 10000^(-ip/64); log2(10000)=13.287712379549449
                const float freq = exp2f(-(float)ip * (13.287712379549449f / 64.f));
                const float ang  = sp * freq;
                float sn, cs;
                sincosf(ang, &sn, &cs);
                sn *= sc; cs *= sc;
                const float e = acc[i][2 * j2];
                const float o = acc[i][2 * j2 + 1];
                v[2 * j2]     = e * cs - o * sn;
                v[2 * j2 + 1] = o * cs + e * sn;
            }
            *(float4*)(orow)     = *(float4*)(v);
            *(float4*)(orow + 4) = *(float4*)(v + 4);
        }
    }
}

// ---------------------------------------------------------------------------
// Retention: for one (b,h) and a 64-row block, loop over 64-col K/V chunks:
//   S = (Q K^T) .* gamma^(n-m) [causal],  Y += S V
// Y written to (B,S,H*D) layout for downstream GroupNorm.
// ---------------------------------------------------------------------------
__global__ __launch_bounds__(256) void retention_kernel(const float* __restrict__ Q,
                                                        const float* __restrict__ K,
                                                        const float* __restrict__ V,
                                                        float* __restrict__ Y)
{
    const int t  = threadIdx.x;
    const int ty = t >> 4, tx = t & 15;
    const int r0 = blockIdx.x * 64;
    const int bh = blockIdx.y;
    const int bidx = bh >> 3;
    const int h    = bh & 7;

    __shared__ float Qs[128][68];  // [e][r], padded: rows 272B (16B aligned)
    __shared__ float Ks[128][68];  // [e][m]
    __shared__ float Vs[64][128];  // [m][c]
    __shared__ float Ss[64][68];   // [r][m]

    // gamma_h = 1 - exp(linspace(log(1/32), log(1/512), 8)[h])
    const float lga = -3.4657359027997265f;  // log(1/32)
    const float lgb = -6.2383246250395075f;  // log(1/512)
    const float ge  = lga + (float)h * (lgb - lga) * (1.f / 7.f);
    const float gamma = 1.f - expf(ge);
    const float lg2   = log2f(gamma);

    float yacc[4][8] = {};

    // Stage Q block (transpose into LDS)
    const float* Qbase = Q + ((size_t)bh * Sc + r0) * Dc;
    {
        const int r  = t >> 2;
        const int e0 = (t & 3) * 32;
#pragma unroll
        for (int q8 = 0; q8 < 8; ++q8) {
            float4 v = *(const float4*)(Qbase + (size_t)r * Dc + e0 + q8 * 4);
            Qs[e0 + q8 * 4 + 0][r] = v.x;
            Qs[e0 + q8 * 4 + 1][r] = v.y;
            Qs[e0 + q8 * 4 + 2][r] = v.z;
            Qs[e0 + q8 * 4 + 3][r] = v.w;
        }
    }

    // Skip chunks whose max decay weight < 1e-12 (negligible vs 2% tolerance)
    const float cutoff = 27.631021f / (-logf(gamma));
    int m_min = r0 - (int)cutoff;
    if (m_min < 0) m_min = 0;
    const int c_lo = m_min >> 6;
    const int c_hi = r0 >> 6;   // diagonal chunk

    for (int c = c_lo; c <= c_hi; ++c) {
        const int c0 = c * 64;
        // Stage K (transposed) and V (row-major)
        const float* Kbase = K + ((size_t)bh * Sc + c0) * Dc;
        const float* Vbase = V + ((size_t)bh * Sc + c0) * Dc;
        {
            const int m  = t >> 2;
            const int e0 = (t & 3) * 32;
#pragma unroll
            for (int q8 = 0; q8 < 8; ++q8) {
                float4 kv = *(const float4*)(Kbase + (size_t)m * Dc + e0 + q8 * 4);
                Ks[e0 + q8 * 4 + 0][m] = kv.x;
                Ks[e0 + q8 * 4 + 1][m] = kv.y;
                Ks[e0 + q8 * 4 + 2][m] = kv.z;
                Ks[e0 + q8 * 4 + 3][m] = kv.w;
                float4 vv = *(const float4*)(Vbase + (size_t)m * Dc + e0 + q8 * 4);
                *(float4*)&Vs[m][e0 + q8 * 4] = vv;
            }
        }
        __syncthreads();

        // Phase A: S tile (rows ty*4+i, cols tx*4+j)
        float sacc[4][4] = {};
#pragma unroll 4
        for (int e = 0; e < 128; ++e) {
            float qa[4], kb[4];
            *(float4*)(qa) = *(const float4*)&Qs[e][ty * 4];
            *(float4*)(kb) = *(const float4*)&Ks[e][tx * 4];
#pragma unroll
            for (int i = 0; i < 4; ++i)
#pragma unroll
                for (int j = 0; j < 4; ++j)
                    sacc[i][j] = fmaf(qa[i], kb[j], sacc[i][j]);
        }
#pragma unroll
        for (int i = 0; i < 4; ++i)
#pragma unroll
            for (int j = 0; j < 4; ++j) {
                const int n = r0 + ty * 4 + i;
                const int m = c0 + tx * 4 + j;
                const int diff = n - m;
                const float w = (diff >= 0) ? exp2f(lg2 * (float)diff) : 0.f;
                Ss[ty * 4 + i][tx * 4 + j] = sacc[i][j] * w;
            }
        __syncthreads();

        // Phase B: Y += S V (rows ty*4+i, cols tx+16*j)
#pragma unroll 4
        for (int m = 0; m < 64; ++m) {
            float sv[4], vv[8];
#pragma unroll
            for (int i = 0; i < 4; ++i) sv[i] = Ss[ty * 4 + i][m];
#pragma unroll
            for (int j = 0; j < 8; ++j) vv[j] = Vs[m][tx + 16 * j];
#pragma unroll
            for (int i = 0; i < 4; ++i)
#pragma unroll
                for (int j = 0; j < 8; ++j)
                    yacc[i][j] = fmaf(sv[i], vv[j], yacc[i][j]);
        }
        __syncthreads();
    }

    // Write Y to (B, S, H*D)
#pragma unroll
    for (int i = 0; i < 4; ++i) {
        const int s = r0 + ty * 4 + i;
        float* yrow = Y + ((size_t)bidx * Sc + s) * Ec + h * Dc;
#pragma unroll
        for (int j = 0; j < 8; ++j)
            yrow[tx + 16 * j] = yacc[i][j];
    }
}

// ---------------------------------------------------------------------------
// GroupNorm (per (b,s,h) over D=128) * gn_weight + gn_bias, times silu-gate.
// 2 rows per 256-thread block; 16 lanes per head group.
// ---------------------------------------------------------------------------
__global__ __launch_bounds__(256) void gn_gate_kernel(const float* __restrict__ Y,
                                                      const float* __restrict__ G,
                                                      const float* __restrict__ gw,
                                                      const float* __restrict__ gbias,
                                                      float* __restrict__ Z)
{
    const int row = blockIdx.x * 2 + (threadIdx.x >> 7);
    const int tr  = threadIdx.x & 127;

    const float* yp = Y + (size_t)row * Ec + tr * 8;
    float v[8];
    *(float4*)(v)     = *(const float4*)(yp);
    *(float4*)(v + 4) = *(const float4*)(yp + 4);

    float s = 0.f, sq = 0.f;
#pragma unroll
    for (int k = 0; k < 8; ++k) { s += v[k]; sq += v[k] * v[k]; }
#pragma unroll
    for (int o = 1; o < 16; o <<= 1) {
        s  += __shfl_xor(s, o, 64);
        sq += __shfl_xor(sq, o, 64);
    }
    const float mu  = s * (1.f / 128.f);
    const float var = sq * (1.f / 128.f) - mu * mu;
    const float inv = rsqrtf(var + 1e-5f);

    const float* gp = G + (size_t)row * Ec + tr * 8;
    float g[8], w8[8], b8[8];
    *(float4*)(g)      = *(const float4*)(gp);
    *(float4*)(g + 4)  = *(const float4*)(gp + 4);
    *(float4*)(w8)     = *(const float4*)(gw + tr * 8);
    *(float4*)(w8 + 4) = *(const float4*)(gw + tr * 8 + 4);
    *(float4*)(b8)     = *(const float4*)(gbias + tr * 8);
    *(float4*)(b8 + 4) = *(const float4*)(gbias + tr * 8 + 4);

    float zo[8];
#pragma unroll
    for (int k = 0; k < 8; ++k)
        zo[k] = ((v[k] - mu) * inv * w8[k] + b8[k]) * g[k];

    float* zp = Z + (size_t)row * Ec + tr * 8;
    *(float4*)(zp)     = *(float4*)(zo);
    *(float4*)(zp + 4) = *(float4*)(zo + 4);
}

} // anonymous namespace

extern "C" void kernel_launch(void* const* d_in, const int* in_sizes, int n_in,
                              void* d_out, int out_size, void* d_ws, size_t ws_size,
                              hipStream_t stream)
{
    const float* X    = (const float*)d_in[0];
    const float* W_Q  = (const float*)d_in[1];
    const float* W_K  = (const float*)d_in[2];
    const float* W_V  = (const float*)d_in[3];
    const float* W_G  = (const float*)d_in[4];
    const float* W_O  = (const float*)d_in[5];
    const float* gw   = (const float*)d_in[6];
    const float* gb   = (const float*)d_in[7];
    float* out = (float*)d_out;

    const size_t SZ = (size_t)Bc * Sc * Ec;   // 4 Mi elements
    float* Qb = (float*)d_ws;
    float* Kb = Qb + SZ;
    float* Vb = Kb + SZ;
    float* Yb = Vb + SZ;
    float* Gb = Kb;   // K dead after retention
    float* Zb = Qb;   // Q dead after retention

    dim3 blk(256);
    proj_kernel<1><<<dim3(Mc / 128, Hc), blk, 0, stream>>>(X, W_Q, Qb);
    proj_kernel<2><<<dim3(Mc / 128, Hc), blk, 0, stream>>>(X, W_K, Kb);
    proj_kernel<0><<<dim3(Mc / 128, Hc), blk, 0, stream>>>(X, W_V, Vb);
    retention_kernel<<<dim3(Sc / 64, Bc * Hc), blk, 0, stream>>>(Qb, Kb, Vb, Yb);
    gemm_kernel<1><<<dim3(Mc / 128, Ec / 128), blk, 0, stream>>>(X, W_G, Gb);
    gn_gate_kernel<<<dim3(Mc / 2), blk, 0, stream>>>(Yb, Gb, gw, gb, Zb);
    gemm_kernel<0><<<dim3(Mc / 128, Ec / 128), blk, 0, stream>>>(Zb, W_O, out);
}

// Round 2
// 268.006 us; speedup vs baseline: 5.9214x; 5.9214x over previous
//
#include <hip/hip_runtime.h>
#include <hip/hip_bf16.h>
#include <math.h>

namespace {

constexpr int Bc = 2;
constexpr int Sc = 2048;
constexpr int Ec = 1024;
constexpr int Hc = 8;
constexpr int Dc = 128;
constexpr int Mc = Bc * Sc; // 4096

typedef unsigned short u16;
typedef u16    u16x8  __attribute__((ext_vector_type(8)));
typedef __bf16 bf16x8 __attribute__((ext_vector_type(8)));
typedef float  f32x4  __attribute__((ext_vector_type(4)));

static __device__ inline bf16x8 asbf(u16x8 v) { return __builtin_bit_cast(bf16x8, v); }

static __device__ inline f32x4 mfma16(u16x8 a, u16x8 b, f32x4 c) {
    return __builtin_amdgcn_mfma_f32_16x16x32_bf16(asbf(a), asbf(b), c, 0, 0, 0);
}

static __device__ inline u16 f2bf(float f) {
    unsigned u = __builtin_bit_cast(unsigned, f);
    return (u16)((u + 0x7fffu + ((u >> 16) & 1u)) >> 16);
}
static __device__ inline float bf2f(u16 h) {
    unsigned u = ((unsigned)h) << 16;
    return __builtin_bit_cast(float, u);
}

// ---------------------------------------------------------------------------
// X f32 -> bf16, flat.
// ---------------------------------------------------------------------------
__global__ __launch_bounds__(256) void convX(const float* __restrict__ in,
                                             u16* __restrict__ out, int n8)
{
    int i = blockIdx.x * 256 + threadIdx.x;
    if (i >= n8) return;
    float4 a = *(const float4*)(in + (size_t)i * 8);
    float4 b = *(const float4*)(in + (size_t)i * 8 + 4);
    u16x8 o;
    o[0] = f2bf(a.x); o[1] = f2bf(a.y); o[2] = f2bf(a.z); o[3] = f2bf(a.w);
    o[4] = f2bf(b.x); o[5] = f2bf(b.y); o[6] = f2bf(b.z); o[7] = f2bf(b.w);
    *(u16x8*)(out + (size_t)i * 8) = o;
}

// ---------------------------------------------------------------------------
// Tiled transpose + convert: out[z][c][r] = bf16(in[z][r][c]).  in: R x C.
// ---------------------------------------------------------------------------
__global__ __launch_bounds__(256) void tconv(const float* __restrict__ in,
                                             u16* __restrict__ out,
                                             int R, int C, size_t in_zs, size_t out_zs)
{
    const float* ip = in + blockIdx.z * in_zs;
    u16* op = out + blockIdx.z * out_zs;
    __shared__ float tile[32][33];
    const int r0 = blockIdx.x * 32, c0 = blockIdx.y * 32;
    const int ty = threadIdx.x >> 5, tx = threadIdx.x & 31;
#pragma unroll
    for (int i = ty; i < 32; i += 8) tile[i][tx] = ip[(size_t)(r0 + i) * C + c0 + tx];
    __syncthreads();
#pragma unroll
    for (int i = ty; i < 32; i += 8) op[(size_t)(c0 + i) * R + r0 + tx] = f2bf(tile[tx][i]);
}

// ---------------------------------------------------------------------------
// xPos trig tables: tabQ[s*64+ip] = (cos*scale, sin*scale), tabK = /scale.
// ---------------------------------------------------------------------------
__global__ __launch_bounds__(256) void trigk(float2* __restrict__ tabQ,
                                             float2* __restrict__ tabK)
{
    int t = blockIdx.x * 256 + threadIdx.x; // 2048*64
    int s = t >> 6, ip = t & 63;
    float sv = (2.f * (float)ip + 51.2f) * (1.f / 179.2f);
    float sc = exp2f(((float)s * (1.f / 512.f)) * log2f(sv));
    float freq = exp2f(-(float)ip * (13.287712379549449f / 64.f));
    float ang = (float)s * freq;
    float sn, cs;
    sincosf(ang, &sn, &cs);
    tabQ[t] = make_float2(cs * sc, sn * sc);
    tabK[t] = make_float2(cs / sc, sn / sc);
}

// ---------------------------------------------------------------------------
// MFMA GEMM: C[4096][1024] = A[4096][1024] x B, B given pre-transposed as
// Bt[n][k].  128x128 tile, BK=32, 4 waves, 16x16x32 bf16 MFMA.
// EPI: 0 plain->bf16, 1 silu->bf16, 2 xposQ->bf16, 3 xposK->bf16, 4 plain->f32
// ---------------------------------------------------------------------------
template<int EPI>
__global__ __launch_bounds__(256) void mgemm(const u16* __restrict__ A,
                                             const u16* __restrict__ Bt,
                                             void* __restrict__ Cout,
                                             const float2* __restrict__ tab)
{
    const int t = threadIdx.x;
    const int lane = t & 63, w = t >> 6;
    const int rl = lane & 15, hi = lane >> 4;
    const int r0 = blockIdx.x * 128;
    const int n0 = blockIdx.y * 128;

    __shared__ u16 As[128][40]; // stride 80B: 2-way banks, 16B aligned
    __shared__ u16 Bs[128][40];

    f32x4 acc[2][8] = {};

    const int srow = t >> 1;
    const int sk   = (t & 1) * 16;
    const u16* Ap = A  + (size_t)(r0 + srow) * Ec + sk;
    const u16* Bp = Bt + (size_t)(n0 + srow) * Ec + sk;

    for (int k0 = 0; k0 < Ec; k0 += 32) {
        u16x8 a0 = *(const u16x8*)(Ap + k0);
        u16x8 a1 = *(const u16x8*)(Ap + k0 + 8);
        u16x8 b0 = *(const u16x8*)(Bp + k0);
        u16x8 b1 = *(const u16x8*)(Bp + k0 + 8);
        __syncthreads();
        *(u16x8*)&As[srow][sk]     = a0;
        *(u16x8*)&As[srow][sk + 8] = a1;
        *(u16x8*)&Bs[srow][sk]     = b0;
        *(u16x8*)&Bs[srow][sk + 8] = b1;
        __syncthreads();
        u16x8 bfr[8];
#pragma unroll
        for (int ct = 0; ct < 8; ++ct)
            bfr[ct] = *(const u16x8*)&Bs[ct * 16 + rl][hi * 8];
#pragma unroll
        for (int rt = 0; rt < 2; ++rt) {
            u16x8 afr = *(const u16x8*)&As[w * 32 + rt * 16 + rl][hi * 8];
#pragma unroll
            for (int ct = 0; ct < 8; ++ct)
                acc[rt][ct] = mfma16(afr, bfr[ct], acc[rt][ct]);
        }
    }

    // Epilogue
#pragma unroll
    for (int rt = 0; rt < 2; ++rt)
#pragma unroll
        for (int ct = 0; ct < 8; ++ct)
#pragma unroll
            for (int reg = 0; reg < 4; ++reg) {
                const int row = r0 + w * 32 + rt * 16 + hi * 4 + reg;
                const int col = n0 + ct * 16 + rl;
                float v = acc[rt][ct][reg];
                if (EPI == 0) {
                    ((u16*)Cout)[(size_t)row * Ec + col] = f2bf(v);
                } else if (EPI == 1) {
                    v = v / (1.f + expf(-v));
                    ((u16*)Cout)[(size_t)row * Ec + col] = f2bf(v);
                } else if (EPI == 2 || EPI == 3) {
                    float p = __shfl_xor(v, 1);
                    const float2 cssn = tab[(size_t)(row & 2047) * 64 + ((col >> 1) & 63)];
                    float o = (lane & 1) ? (v * cssn.x + p * cssn.y)
                                         : (v * cssn.x - p * cssn.y);
                    ((u16*)Cout)[(size_t)row * Ec + col] = f2bf(o);
                } else {
                    ((float*)Cout)[(size_t)row * Ec + col] = v;
                }
            }
}

// ---------------------------------------------------------------------------
// Retention with MFMA.  Block = (64 Q-rows, one (b,h)).  4 waves; wave w owns
// 16 rows.  Per 64-col chunk: S = (Q K^T) * gamma^(n-m) [causal], Y += S V.
// Q frags register-resident; S round-trips LDS in bf16; V staged transposed.
// ---------------------------------------------------------------------------
__global__ __launch_bounds__(256) void ret_mfma(const u16* __restrict__ Q,
                                                const u16* __restrict__ K,
                                                const u16* __restrict__ V,
                                                float* __restrict__ Y)
{
    const int t = threadIdx.x, lane = t & 63, w = t >> 6;
    const int rl = lane & 15, hi = lane >> 4;
    const int rb = blockIdx.x, bh = blockIdx.y;
    const int b = bh >> 3, h = bh & 7;

    __shared__ u16 QS[64][136]; // Q staging; reused as Ss[64][72] in chunk loop
    __shared__ u16 Ks[64][136];
    __shared__ u16 Vt[128][72]; // V transposed: Vt[d][m]
    u16* Ss = &QS[0][0];

    const float lga = -3.4657359027997265f; // log(1/32)
    const float lgb = -6.2383246250395075f; // log(1/512)
    const float gamma = 1.f - expf(lga + (float)h * (lgb - lga) * (1.f / 7.f));
    const float lg2 = log2f(gamma);

    // Stage Q (rows rb*64..+63)
    {
        const int i = t >> 2, q = (t & 3) * 32;
        const u16* Qg = Q + (size_t)(b * Sc + rb * 64 + i) * Ec + h * Dc + q;
        u16x8 v0 = *(const u16x8*)(Qg);
        u16x8 v1 = *(const u16x8*)(Qg + 8);
        u16x8 v2 = *(const u16x8*)(Qg + 16);
        u16x8 v3 = *(const u16x8*)(Qg + 24);
        *(u16x8*)&QS[i][q]      = v0;
        *(u16x8*)&QS[i][q + 8]  = v1;
        *(u16x8*)&QS[i][q + 16] = v2;
        *(u16x8*)&QS[i][q + 24] = v3;
    }
    __syncthreads();
    u16x8 qf[4];
#pragma unroll
    for (int ks = 0; ks < 4; ++ks)
        qf[ks] = *(const u16x8*)&QS[w * 16 + rl][ks * 32 + hi * 8];
    __syncthreads(); // all Q-frag reads done before Ss overwrites QS

    f32x4 yacc[8] = {};

    int c_lo = 0;
    {
        float cut = 27.631021f / (-logf(gamma)); // weight >= ~1e-12
        int mmin = rb * 64 - (int)cut;
        if (mmin > 0) c_lo = mmin >> 6;
    }

    for (int c = c_lo; c <= rb; ++c) {
        // stage K chunk (row-major)
        {
            const int i = t >> 2, q = (t & 3) * 32;
            const u16* Kg = K + (size_t)(b * Sc + c * 64 + i) * Ec + h * Dc + q;
            u16x8 v0 = *(const u16x8*)(Kg);
            u16x8 v1 = *(const u16x8*)(Kg + 8);
            u16x8 v2 = *(const u16x8*)(Kg + 16);
            u16x8 v3 = *(const u16x8*)(Kg + 24);
            *(u16x8*)&Ks[i][q]      = v0;
            *(u16x8*)&Ks[i][q + 8]  = v1;
            *(u16x8*)&Ks[i][q + 16] = v2;
            *(u16x8*)&Ks[i][q + 24] = v3;
        }
        // stage V chunk transposed
        {
            const int m = t & 63, dseg = (t >> 6) * 8;
#pragma unroll
            for (int p = 0; p < 4; ++p) {
                const int d0 = dseg + p * 32;
                u16x8 vv = *(const u16x8*)(V + (size_t)(b * Sc + c * 64 + m) * Ec + h * Dc + d0);
#pragma unroll
                for (int j = 0; j < 8; ++j) Vt[d0 + j][m] = vv[j];
            }
        }
        __syncthreads();

        // QK^T + decay -> Ss (bf16)
        float rf[4];
#pragma unroll
        for (int reg = 0; reg < 4; ++reg) {
            const int nloc = w * 16 + hi * 4 + reg;
            rf[reg] = exp2f(lg2 * (float)(rb * 64 + nloc - c * 64));
        }
#pragma unroll
        for (int mt = 0; mt < 4; ++mt) {
            f32x4 s = {};
#pragma unroll
            for (int ks = 0; ks < 4; ++ks) {
                u16x8 kf = *(const u16x8*)&Ks[mt * 16 + rl][ks * 32 + hi * 8];
                s = mfma16(qf[ks], kf, s);
            }
            const int min_ = mt * 16 + rl;
            const float cf = exp2f(-lg2 * (float)min_);
#pragma unroll
            for (int reg = 0; reg < 4; ++reg) {
                const int nloc = w * 16 + hi * 4 + reg;
                float wgt = rf[reg] * cf;
                if (c == rb && min_ > nloc) wgt = 0.f;
                Ss[nloc * 72 + min_] = f2bf(s[reg] * wgt);
            }
        }
        __syncthreads();

        // Y += S V
        u16x8 sf0 = *(const u16x8*)&Ss[(w * 16 + rl) * 72 + hi * 8];
        u16x8 sf1 = *(const u16x8*)&Ss[(w * 16 + rl) * 72 + 32 + hi * 8];
#pragma unroll
        for (int ct = 0; ct < 8; ++ct) {
            u16x8 vf0 = *(const u16x8*)&Vt[ct * 16 + rl][hi * 8];
            u16x8 vf1 = *(const u16x8*)&Vt[ct * 16 + rl][32 + hi * 8];
            yacc[ct] = mfma16(sf0, vf0, yacc[ct]);
            yacc[ct] = mfma16(sf1, vf1, yacc[ct]);
        }
        __syncthreads();
    }

    // Write Y (f32, (B,S,H*D) layout)
#pragma unroll
    for (int ct = 0; ct < 8; ++ct)
#pragma unroll
        for (int reg = 0; reg < 4; ++reg) {
            const int nloc = w * 16 + hi * 4 + reg;
            Y[(size_t)(b * Sc + rb * 64 + nloc) * Ec + h * Dc + ct * 16 + rl] = yacc[ct][reg];
        }
}

// ---------------------------------------------------------------------------
// GroupNorm (per (b,s,h) over D=128) * gn_weight + gn_bias, times gate. -> bf16
// ---------------------------------------------------------------------------
__global__ __launch_bounds__(256) void gn_gate(const float* __restrict__ Y,
                                               const u16* __restrict__ G,
                                               const float* __restrict__ gw,
                                               const float* __restrict__ gbias,
                                               u16* __restrict__ Z)
{
    const int row = blockIdx.x * 2 + (threadIdx.x >> 7);
    const int tr  = threadIdx.x & 127;

    const float* yp = Y + (size_t)row * Ec + tr * 8;
    float v[8];
    *(float4*)(v)     = *(const float4*)(yp);
    *(float4*)(v + 4) = *(const float4*)(yp + 4);

    float s = 0.f, sq = 0.f;
#pragma unroll
    for (int k = 0; k < 8; ++k) { s += v[k]; sq += v[k] * v[k]; }
#pragma unroll
    for (int o = 1; o < 16; o <<= 1) {
        s  += __shfl_xor(s, o, 64);
        sq += __shfl_xor(sq, o, 64);
    }
    const float mu  = s * (1.f / 128.f);
    const float var = sq * (1.f / 128.f) - mu * mu;
    const float inv = rsqrtf(var + 1e-5f);

    u16x8 gv = *(const u16x8*)(G + (size_t)row * Ec + tr * 8);
    float w8[8], b8[8];
    *(float4*)(w8)     = *(const float4*)(gw + tr * 8);
    *(float4*)(w8 + 4) = *(const float4*)(gw + tr * 8 + 4);
    *(float4*)(b8)     = *(const float4*)(gbias + tr * 8);
    *(float4*)(b8 + 4) = *(const float4*)(gbias + tr * 8 + 4);

    u16x8 zo;
#pragma unroll
    for (int k = 0; k < 8; ++k)
        zo[k] = f2bf(((v[k] - mu) * inv * w8[k] + b8[k]) * bf2f(gv[k]));

    *(u16x8*)(Z + (size_t)row * Ec + tr * 8) = zo;
}

} // anonymous namespace

extern "C" void kernel_launch(void* const* d_in, const int* in_sizes, int n_in,
                              void* d_out, int out_size, void* d_ws, size_t ws_size,
                              hipStream_t stream)
{
    const float* X    = (const float*)d_in[0];
    const float* W_Q  = (const float*)d_in[1];
    const float* W_K  = (const float*)d_in[2];
    const float* W_V  = (const float*)d_in[3];
    const float* W_G  = (const float*)d_in[4];
    const float* W_O  = (const float*)d_in[5];
    const float* gw   = (const float*)d_in[6];
    const float* gb   = (const float*)d_in[7];

    char* ws = (char*)d_ws;
    const size_t NX = (size_t)Mc * Ec;          // 4 Mi elements
    u16*    Xb   = (u16*)ws;                ws += NX * 2;           // 8 MB
    u16*    WqT  = (u16*)ws;                ws += (size_t)Ec * Ec * 2; // 2 MB
    u16*    WkT  = (u16*)ws;                ws += (size_t)Ec * Ec * 2;
    u16*    WvT  = (u16*)ws;                ws += (size_t)Ec * Ec * 2;
    u16*    WgT  = (u16*)ws;                ws += (size_t)Ec * Ec * 2;
    u16*    WoT  = (u16*)ws;                ws += (size_t)Ec * Ec * 2;
    float2* tabQ = (float2*)ws;             ws += (size_t)Sc * 64 * sizeof(float2); // 1 MB
    float2* tabK = (float2*)ws;             ws += (size_t)Sc * 64 * sizeof(float2);
    u16*    Qb   = (u16*)ws;                ws += NX * 2;           // 8 MB
    u16*    Kb   = (u16*)ws;                ws += NX * 2;
    u16*    Vb   = (u16*)ws;                ws += NX * 2;
    float*  Yb   = (float*)ws;              ws += NX * 4;           // 16 MB
    u16*    Gb   = Qb;  // Q dead after retention
    u16*    Zb   = Kb;  // K dead after retention

    dim3 blk(256);
    convX<<<dim3((int)(NX / 8 / 256)), blk, 0, stream>>>(X, Xb, (int)(NX / 8));
    tconv<<<dim3(32, 4, 8), blk, 0, stream>>>(W_Q, WqT, Ec, Dc, (size_t)Ec * Dc, (size_t)Dc * Ec);
    tconv<<<dim3(32, 4, 8), blk, 0, stream>>>(W_K, WkT, Ec, Dc, (size_t)Ec * Dc, (size_t)Dc * Ec);
    tconv<<<dim3(32, 4, 8), blk, 0, stream>>>(W_V, WvT, Ec, Dc, (size_t)Ec * Dc, (size_t)Dc * Ec);
    tconv<<<dim3(32, 32, 1), blk, 0, stream>>>(W_G, WgT, Ec, Ec, 0, 0);
    tconv<<<dim3(32, 32, 1), blk, 0, stream>>>(W_O, WoT, Ec, Ec, 0, 0);
    trigk<<<dim3(Sc * 64 / 256), blk, 0, stream>>>(tabQ, tabK);

    mgemm<2><<<dim3(Mc / 128, Ec / 128), blk, 0, stream>>>(Xb, WqT, Qb, tabQ);
    mgemm<3><<<dim3(Mc / 128, Ec / 128), blk, 0, stream>>>(Xb, WkT, Kb, tabK);
    mgemm<0><<<dim3(Mc / 128, Ec / 128), blk, 0, stream>>>(Xb, WvT, Vb, nullptr);

    ret_mfma<<<dim3(Sc / 64, Bc * Hc), blk, 0, stream>>>(Qb, Kb, Vb, Yb);

    mgemm<1><<<dim3(Mc / 128, Ec / 128), blk, 0, stream>>>(Xb, WgT, Gb, nullptr);
    gn_gate<<<dim3(Mc / 2), blk, 0, stream>>>(Yb, Gb, gw, gb, Zb);
    mgemm<4><<<dim3(Mc / 128, Ec / 128), blk, 0, stream>>>(Zb, WoT, d_out, nullptr);
}

// Round 3
// 192.212 us; speedup vs baseline: 8.2563x; 1.3943x over previous
//
#include <hip/hip_runtime.h>
#include <hip/hip_bf16.h>
#include <math.h>

namespace {

constexpr int Bc = 2;
constexpr int Sc = 2048;
constexpr int Ec = 1024;
constexpr int Hc = 8;
constexpr int Dc = 128;
constexpr int Mc = Bc * Sc; // 4096

typedef unsigned short u16;
typedef u16    u16x8  __attribute__((ext_vector_type(8)));
typedef u16    u16x4  __attribute__((ext_vector_type(4)));
typedef __bf16 bf16x8 __attribute__((ext_vector_type(8)));
typedef float  f32x4  __attribute__((ext_vector_type(4)));

static __device__ inline bf16x8 asbf(u16x8 v) { return __builtin_bit_cast(bf16x8, v); }

static __device__ inline f32x4 mfma16(u16x8 a, u16x8 b, f32x4 c) {
    return __builtin_amdgcn_mfma_f32_16x16x32_bf16(asbf(a), asbf(b), c, 0, 0, 0);
}

static __device__ inline u16 f2bf(float f) {
    unsigned u = __builtin_bit_cast(unsigned, f);
    return (u16)((u + 0x7fffu + ((u >> 16) & 1u)) >> 16);
}
static __device__ inline float bf2f(u16 h) {
    unsigned u = ((unsigned)h) << 16;
    return __builtin_bit_cast(float, u);
}

// ---------------------------------------------------------------------------
// X f32 -> bf16, flat.
// ---------------------------------------------------------------------------
__global__ __launch_bounds__(256) void convX(const float* __restrict__ in,
                                             u16* __restrict__ out, int n8)
{
    int i = blockIdx.x * 256 + threadIdx.x;
    if (i >= n8) return;
    float4 a = *(const float4*)(in + (size_t)i * 8);
    float4 b = *(const float4*)(in + (size_t)i * 8 + 4);
    u16x8 o;
    o[0] = f2bf(a.x); o[1] = f2bf(a.y); o[2] = f2bf(a.z); o[3] = f2bf(a.w);
    o[4] = f2bf(b.x); o[5] = f2bf(b.y); o[6] = f2bf(b.z); o[7] = f2bf(b.w);
    *(u16x8*)(out + (size_t)i * 8) = o;
}

// ---------------------------------------------------------------------------
// Tiled transpose + convert: out[z][c][r] = bf16(in[z][r][c]).  in: R x C.
// ---------------------------------------------------------------------------
__global__ __launch_bounds__(256) void tconv(const float* __restrict__ in,
                                             u16* __restrict__ out,
                                             int R, int C, size_t in_zs, size_t out_zs)
{
    const float* ip = in + blockIdx.z * in_zs;
    u16* op = out + blockIdx.z * out_zs;
    __shared__ float tile[32][33];
    const int r0 = blockIdx.x * 32, c0 = blockIdx.y * 32;
    const int ty = threadIdx.x >> 5, tx = threadIdx.x & 31;
#pragma unroll
    for (int i = ty; i < 32; i += 8) tile[i][tx] = ip[(size_t)(r0 + i) * C + c0 + tx];
    __syncthreads();
#pragma unroll
    for (int i = ty; i < 32; i += 8) op[(size_t)(c0 + i) * R + r0 + tx] = f2bf(tile[tx][i]);
}

// ---------------------------------------------------------------------------
// xPos trig tables: tabQ[s*64+ip] = (cos*scale, sin*scale), tabK = /scale.
// ---------------------------------------------------------------------------
__global__ __launch_bounds__(256) void trigk(float2* __restrict__ tabQ,
                                             float2* __restrict__ tabK)
{
    int t = blockIdx.x * 256 + threadIdx.x; // 2048*64
    int s = t >> 6, ip = t & 63;
    float sv = (2.f * (float)ip + 51.2f) * (1.f / 179.2f);
    float sc = exp2f(((float)s * (1.f / 512.f)) * log2f(sv));
    float freq = exp2f(-(float)ip * (13.287712379549449f / 64.f));
    float ang = (float)s * freq;
    float sn, cs;
    sincosf(ang, &sn, &cs);
    tabQ[t] = make_float2(cs * sc, sn * sc);
    tabK[t] = make_float2(cs / sc, sn / sc);
}

// ---------------------------------------------------------------------------
// MFMA GEMM with one-step register prefetch (T14): C = A x Bt^T.
// 128x128 tile, BK=32, 4 waves, 16x16x32 bf16 MFMA.
// EPI: 0 plain->bf16, 1 silu->bf16, 2 xposQ->bf16, 3 xposK->bf16, 4 plain->f32
// ---------------------------------------------------------------------------
template<int EPI>
__global__ __launch_bounds__(256) void mgemm(const u16* __restrict__ A,
                                             const u16* __restrict__ Bt,
                                             void* __restrict__ Cout,
                                             const float2* __restrict__ tab)
{
    const int t = threadIdx.x;
    const int lane = t & 63, w = t >> 6;
    const int rl = lane & 15, hi = lane >> 4;
    const int r0 = blockIdx.x * 128;
    const int n0 = blockIdx.y * 128;

    __shared__ u16 As[128][40]; // stride 80B: 2-way banks, 16B aligned
    __shared__ u16 Bs[128][40];

    f32x4 acc[2][8] = {};

    const int srow = t >> 1;
    const int sk   = (t & 1) * 16;
    const u16* Ap = A  + (size_t)(r0 + srow) * Ec + sk;
    const u16* Bp = Bt + (size_t)(n0 + srow) * Ec + sk;

    u16x8 a0 = *(const u16x8*)(Ap);
    u16x8 a1 = *(const u16x8*)(Ap + 8);
    u16x8 b0 = *(const u16x8*)(Bp);
    u16x8 b1 = *(const u16x8*)(Bp + 8);

    for (int k0 = 0; k0 < Ec; k0 += 32) {
        __syncthreads();
        *(u16x8*)&As[srow][sk]     = a0;
        *(u16x8*)&As[srow][sk + 8] = a1;
        *(u16x8*)&Bs[srow][sk]     = b0;
        *(u16x8*)&Bs[srow][sk + 8] = b1;
        __syncthreads();
        if (k0 + 32 < Ec) { // prefetch next K-step under the MFMA cluster
            a0 = *(const u16x8*)(Ap + k0 + 32);
            a1 = *(const u16x8*)(Ap + k0 + 40);
            b0 = *(const u16x8*)(Bp + k0 + 32);
            b1 = *(const u16x8*)(Bp + k0 + 40);
        }
        u16x8 bfr[8];
#pragma unroll
        for (int ct = 0; ct < 8; ++ct)
            bfr[ct] = *(const u16x8*)&Bs[ct * 16 + rl][hi * 8];
#pragma unroll
        for (int rt = 0; rt < 2; ++rt) {
            u16x8 afr = *(const u16x8*)&As[w * 32 + rt * 16 + rl][hi * 8];
#pragma unroll
            for (int ct = 0; ct < 8; ++ct)
                acc[rt][ct] = mfma16(afr, bfr[ct], acc[rt][ct]);
        }
    }

    // Epilogue
#pragma unroll
    for (int rt = 0; rt < 2; ++rt)
#pragma unroll
        for (int ct = 0; ct < 8; ++ct)
#pragma unroll
            for (int reg = 0; reg < 4; ++reg) {
                const int row = r0 + w * 32 + rt * 16 + hi * 4 + reg;
                const int col = n0 + ct * 16 + rl;
                float v = acc[rt][ct][reg];
                if (EPI == 0) {
                    ((u16*)Cout)[(size_t)row * Ec + col] = f2bf(v);
                } else if (EPI == 1) {
                    v = v / (1.f + expf(-v));
                    ((u16*)Cout)[(size_t)row * Ec + col] = f2bf(v);
                } else if (EPI == 2 || EPI == 3) {
                    float p = __shfl_xor(v, 1);
                    const float2 cssn = tab[(size_t)(row & 2047) * 64 + ((col >> 1) & 63)];
                    float o = (lane & 1) ? (v * cssn.x + p * cssn.y)
                                         : (v * cssn.x - p * cssn.y);
                    ((u16*)Cout)[(size_t)row * Ec + col] = f2bf(o);
                } else {
                    ((float*)Cout)[(size_t)row * Ec + col] = v;
                }
            }
}

// ---------------------------------------------------------------------------
// Retention + fused GroupNorm*gate.  Block = (64 Q-rows, one (b,h)), 4 waves.
// 1-D grid of 512: id = rbidx*16 + bh, rb = 31 - rbidx  (heavy blocks first,
// same-bh blocks share an XCD under round-robin dispatch).
// Per chunk: S = (Q K^T) * gamma^(n-m) [causal], Y += S V, with next chunk's
// K/V prefetched into registers (T14).  Epilogue: per-head GroupNorm, * gate,
// write Z (bf16).
// ---------------------------------------------------------------------------
__global__ __launch_bounds__(256) void ret_gn(const u16* __restrict__ Q,
                                              const u16* __restrict__ K,
                                              const u16* __restrict__ V,
                                              const u16* __restrict__ G,
                                              const float* __restrict__ gw,
                                              const float* __restrict__ gbias,
                                              u16* __restrict__ Z)
{
    const int t = threadIdx.x, lane = t & 63, w = t >> 6;
    const int rl = lane & 15, hi = lane >> 4;
    const int id = blockIdx.x;
    const int bh = id & 15, rb = 31 - (id >> 4);
    const int b = bh >> 3, h = bh & 7;

    __shared__ u16 Ks[64][136]; // also Q staging
    __shared__ u16 Vt[128][72]; // V transposed: Vt[d][m]
    __shared__ u16 Ss[64][72];

    const float lga = -3.4657359027997265f; // log(1/32)
    const float lgb = -6.2383246250395075f; // log(1/512)
    const float gamma = 1.f - expf(lga + (float)h * (lgb - lga) * (1.f / 7.f));
    const float lg2 = log2f(gamma);

    // ---- stage Q via Ks, pull frags to registers ----
    {
        const int i = t >> 2, q = (t & 3) * 32;
        const u16* Qg = Q + (size_t)(b * Sc + rb * 64 + i) * Ec + h * Dc + q;
        u16x8 v0 = *(const u16x8*)(Qg);
        u16x8 v1 = *(const u16x8*)(Qg + 8);
        u16x8 v2 = *(const u16x8*)(Qg + 16);
        u16x8 v3 = *(const u16x8*)(Qg + 24);
        *(u16x8*)&Ks[i][q]      = v0;
        *(u16x8*)&Ks[i][q + 8]  = v1;
        *(u16x8*)&Ks[i][q + 16] = v2;
        *(u16x8*)&Ks[i][q + 24] = v3;
    }
    __syncthreads();
    u16x8 qf[4];
#pragma unroll
    for (int ks = 0; ks < 4; ++ks)
        qf[ks] = *(const u16x8*)&Ks[w * 16 + rl][ks * 32 + hi * 8];

    int c_lo = 0;
    {
        float cut = 9.2103404f / (-logf(gamma)); // weight >= ~1e-4
        int mmin = rb * 64 - (int)cut;
        if (mmin > 0) c_lo = mmin >> 6;
    }

    // per-lane staging geometry
    const int ki = t >> 2,      kq  = (t & 3) * 32;   // K: row, 32-elem quarter
    const int vm4 = (t & 15) * 4, vd = (t >> 4) * 8;  // V: 4 rows, 8-d segment
    const u16* Kg0 = K + (size_t)(b * Sc) * Ec + h * Dc;
    const u16* Vg0 = V + (size_t)(b * Sc) * Ec + h * Dc;

    u16x8 kreg[4], vreg[4];
    {
        const u16* Kg = Kg0 + (size_t)(c_lo * 64 + ki) * Ec + kq;
#pragma unroll
        for (int r = 0; r < 4; ++r) kreg[r] = *(const u16x8*)(Kg + r * 8);
        const u16* Vg = Vg0 + (size_t)(c_lo * 64 + vm4) * Ec + vd;
#pragma unroll
        for (int r = 0; r < 4; ++r) vreg[r] = *(const u16x8*)(Vg + (size_t)r * Ec);
    }

    // decay factors: wgt(n,m) = rf[reg] * cfm[mt], rf *= gamma^-64 per chunk
    float cfm[4];
#pragma unroll
    for (int mt = 0; mt < 4; ++mt)
        cfm[mt] = exp2f(-lg2 * (float)(mt * 16 + rl));
    float rf[4];
#pragma unroll
    for (int reg = 0; reg < 4; ++reg)
        rf[reg] = exp2f(lg2 * (float)(rb * 64 + w * 16 + hi * 4 + reg - c_lo * 64));
    const float ginv64 = exp2f(-lg2 * 64.f);

    f32x4 yacc[8] = {};

    for (int c = c_lo; c <= rb; ++c) {
        __syncthreads();  // prior-iter LDS reads (and initial qf reads) done
        // regs -> LDS
#pragma unroll
        for (int r = 0; r < 4; ++r)
            *(u16x8*)&Ks[ki][kq + r * 8] = kreg[r];
#pragma unroll
        for (int j = 0; j < 8; ++j) {
            u16x4 p;
            p[0] = vreg[0][j]; p[1] = vreg[1][j]; p[2] = vreg[2][j]; p[3] = vreg[3][j];
            *(u16x4*)&Vt[vd + j][vm4] = p;
        }
        __syncthreads();
        if (c < rb) { // prefetch next chunk under compute
            const u16* Kg = Kg0 + (size_t)((c + 1) * 64 + ki) * Ec + kq;
#pragma unroll
            for (int r = 0; r < 4; ++r) kreg[r] = *(const u16x8*)(Kg + r * 8);
            const u16* Vg = Vg0 + (size_t)((c + 1) * 64 + vm4) * Ec + vd;
#pragma unroll
            for (int r = 0; r < 4; ++r) vreg[r] = *(const u16x8*)(Vg + (size_t)r * Ec);
        }

        // QK^T + decay -> Ss (bf16)
        __builtin_amdgcn_s_setprio(1);
#pragma unroll
        for (int mt = 0; mt < 4; ++mt) {
            f32x4 s = {};
#pragma unroll
            for (int ks = 0; ks < 4; ++ks) {
                u16x8 kf = *(const u16x8*)&Ks[mt * 16 + rl][ks * 32 + hi * 8];
                s = mfma16(qf[ks], kf, s);
            }
            const int min_ = mt * 16 + rl;
#pragma unroll
            for (int reg = 0; reg < 4; ++reg) {
                const int nloc = w * 16 + hi * 4 + reg;
                float wgt = rf[reg] * cfm[mt];
                if (c == rb && min_ > nloc) wgt = 0.f;
                Ss[nloc][min_] = f2bf(s[reg] * wgt);
            }
        }
        __builtin_amdgcn_s_setprio(0);
        __syncthreads();

        // Y += S V
        u16x8 sf0 = *(const u16x8*)&Ss[w * 16 + rl][hi * 8];
        u16x8 sf1 = *(const u16x8*)&Ss[w * 16 + rl][32 + hi * 8];
        __builtin_amdgcn_s_setprio(1);
#pragma unroll
        for (int ct = 0; ct < 8; ++ct) {
            u16x8 vf0 = *(const u16x8*)&Vt[ct * 16 + rl][hi * 8];
            u16x8 vf1 = *(const u16x8*)&Vt[ct * 16 + rl][32 + hi * 8];
            yacc[ct] = mfma16(sf0, vf0, yacc[ct]);
            yacc[ct] = mfma16(sf1, vf1, yacc[ct]);
        }
        __builtin_amdgcn_s_setprio(0);
#pragma unroll
        for (int reg = 0; reg < 4; ++reg) rf[reg] *= ginv64;
    }

    // ---- fused GroupNorm * gate epilogue ----
#pragma unroll
    for (int reg = 0; reg < 4; ++reg) {
        const int nloc = w * 16 + hi * 4 + reg;
        const size_t row = (size_t)(b * Sc + rb * 64 + nloc);
        float s = 0.f, sq = 0.f;
#pragma unroll
        for (int ct = 0; ct < 8; ++ct) {
            float v = yacc[ct][reg];
            s += v; sq += v * v;
        }
#pragma unroll
        for (int o = 1; o < 16; o <<= 1) {
            s  += __shfl_xor(s, o, 64);
            sq += __shfl_xor(sq, o, 64);
        }
        const float mu  = s * (1.f / 128.f);
        const float var = sq * (1.f / 128.f) - mu * mu;
        const float inv = rsqrtf(var + 1e-5f);
#pragma unroll
        for (int ct = 0; ct < 8; ++ct) {
            const int col = h * Dc + ct * 16 + rl;
            const float gate = bf2f(G[row * Ec + col]);
            const float z = ((yacc[ct][reg] - mu) * inv * gw[col] + gbias[col]) * gate;
            Z[row * Ec + col] = f2bf(z);
        }
    }
}

} // anonymous namespace

extern "C" void kernel_launch(void* const* d_in, const int* in_sizes, int n_in,
                              void* d_out, int out_size, void* d_ws, size_t ws_size,
                              hipStream_t stream)
{
    const float* X    = (const float*)d_in[0];
    const float* W_Q  = (const float*)d_in[1];
    const float* W_K  = (const float*)d_in[2];
    const float* W_V  = (const float*)d_in[3];
    const float* W_G  = (const float*)d_in[4];
    const float* W_O  = (const float*)d_in[5];
    const float* gw   = (const float*)d_in[6];
    const float* gb   = (const float*)d_in[7];

    char* ws = (char*)d_ws;
    const size_t NX = (size_t)Mc * Ec;          // 4 Mi elements
    u16*    Xb   = (u16*)ws;                ws += NX * 2;              // 8 MB
    u16*    WqT  = (u16*)ws;                ws += (size_t)Ec * Ec * 2; // 2 MB
    u16*    WkT  = (u16*)ws;                ws += (size_t)Ec * Ec * 2;
    u16*    WvT  = (u16*)ws;                ws += (size_t)Ec * Ec * 2;
    u16*    WgT  = (u16*)ws;                ws += (size_t)Ec * Ec * 2;
    u16*    WoT  = (u16*)ws;                ws += (size_t)Ec * Ec * 2;
    float2* tabQ = (float2*)ws;             ws += (size_t)Sc * 64 * sizeof(float2); // 1 MB
    float2* tabK = (float2*)ws;             ws += (size_t)Sc * 64 * sizeof(float2);
    u16*    Qb   = (u16*)ws;                ws += NX * 2;              // 8 MB
    u16*    Kb   = (u16*)ws;                ws += NX * 2;
    u16*    Vb   = (u16*)ws;                ws += NX * 2;
    u16*    Gb   = (u16*)ws;                ws += NX * 2;
    u16*    Zb   = (u16*)ws;                ws += NX * 2;

    dim3 blk(256);
    convX<<<dim3((int)(NX / 8 / 256)), blk, 0, stream>>>(X, Xb, (int)(NX / 8));
    tconv<<<dim3(32, 4, 8), blk, 0, stream>>>(W_Q, WqT, Ec, Dc, (size_t)Ec * Dc, (size_t)Dc * Ec);
    tconv<<<dim3(32, 4, 8), blk, 0, stream>>>(W_K, WkT, Ec, Dc, (size_t)Ec * Dc, (size_t)Dc * Ec);
    tconv<<<dim3(32, 4, 8), blk, 0, stream>>>(W_V, WvT, Ec, Dc, (size_t)Ec * Dc, (size_t)Dc * Ec);
    tconv<<<dim3(32, 32, 1), blk, 0, stream>>>(W_G, WgT, Ec, Ec, 0, 0);
    tconv<<<dim3(32, 32, 1), blk, 0, stream>>>(W_O, WoT, Ec, Ec, 0, 0);
    trigk<<<dim3(Sc * 64 / 256), blk, 0, stream>>>(tabQ, tabK);

    mgemm<2><<<dim3(Mc / 128, Ec / 128), blk, 0, stream>>>(Xb, WqT, Qb, tabQ);
    mgemm<3><<<dim3(Mc / 128, Ec / 128), blk, 0, stream>>>(Xb, WkT, Kb, tabK);
    mgemm<0><<<dim3(Mc / 128, Ec / 128), blk, 0, stream>>>(Xb, WvT, Vb, nullptr);
    mgemm<1><<<dim3(Mc / 128, Ec / 128), blk, 0, stream>>>(Xb, WgT, Gb, nullptr);

    ret_gn<<<dim3(512), blk, 0, stream>>>(Qb, Kb, Vb, Gb, gw, gb, Zb);

    mgemm<4><<<dim3(Mc / 128, Ec / 128), blk, 0, stream>>>(Zb, WoT, d_out, nullptr);
}

// Round 4
// 157.805 us; speedup vs baseline: 10.0564x; 1.2180x over previous
//
#include <hip/hip_runtime.h>
#include <hip/hip_bf16.h>
#include <math.h>

namespace {

constexpr int Bc = 2;
constexpr int Sc = 2048;
constexpr int Ec = 1024;
constexpr int Hc = 8;
constexpr int Dc = 128;
constexpr int Mc = Bc * Sc; // 4096

typedef unsigned short u16;
typedef u16    u16x8  __attribute__((ext_vector_type(8)));
typedef u16    u16x4  __attribute__((ext_vector_type(4)));
typedef __bf16 bf16x8 __attribute__((ext_vector_type(8)));
typedef float  f32x4  __attribute__((ext_vector_type(4)));

static __device__ inline bf16x8 asbf(u16x8 v) { return __builtin_bit_cast(bf16x8, v); }

static __device__ inline f32x4 mfma16(u16x8 a, u16x8 b, f32x4 c) {
    return __builtin_amdgcn_mfma_f32_16x16x32_bf16(asbf(a), asbf(b), c, 0, 0, 0);
}

static __device__ inline u16 f2bf(float f) {
    unsigned u = __builtin_bit_cast(unsigned, f);
    return (u16)((u + 0x7fffu + ((u >> 16) & 1u)) >> 16);
}
static __device__ inline float bf2f(u16 h) {
    unsigned u = ((unsigned)h) << 16;
    return __builtin_bit_cast(float, u);
}

// ---------------------------------------------------------------------------
// X f32 -> bf16, flat.
// ---------------------------------------------------------------------------
__global__ __launch_bounds__(256) void convX(const float* __restrict__ in,
                                             u16* __restrict__ out, int n8)
{
    int i = blockIdx.x * 256 + threadIdx.x;
    if (i >= n8) return;
    float4 a = *(const float4*)(in + (size_t)i * 8);
    float4 b = *(const float4*)(in + (size_t)i * 8 + 4);
    u16x8 o;
    o[0] = f2bf(a.x); o[1] = f2bf(a.y); o[2] = f2bf(a.z); o[3] = f2bf(a.w);
    o[4] = f2bf(b.x); o[5] = f2bf(b.y); o[6] = f2bf(b.z); o[7] = f2bf(b.w);
    *(u16x8*)(out + (size_t)i * 8) = o;
}

// ---------------------------------------------------------------------------
// Head-weight transpose+convert: 3 sources [8][1024][128] -> out[z][128][1024].
// z = src*8 + h, src in {0,1,2}.
// ---------------------------------------------------------------------------
__global__ __launch_bounds__(256) void tconvH(const float* __restrict__ p0,
                                              const float* __restrict__ p1,
                                              const float* __restrict__ p2,
                                              u16* __restrict__ out)
{
    const int z = blockIdx.z;
    const float* ip = (z < 8 ? p0 : z < 16 ? p1 : p2) + (size_t)(z & 7) * Ec * Dc;
    u16* op = out + (size_t)z * Dc * Ec;
    __shared__ float tile[32][33];
    const int r0 = blockIdx.x * 32, c0 = blockIdx.y * 32;
    const int ty = threadIdx.x >> 5, tx = threadIdx.x & 31;
#pragma unroll
    for (int i = ty; i < 32; i += 8) tile[i][tx] = ip[(size_t)(r0 + i) * Dc + c0 + tx];
    __syncthreads();
#pragma unroll
    for (int i = ty; i < 32; i += 8) op[(size_t)(c0 + i) * Ec + r0 + tx] = f2bf(tile[tx][i]);
}

// ---------------------------------------------------------------------------
// Square-weight transpose+convert: 2 sources [1024][1024] -> out[z][1024][1024].
// ---------------------------------------------------------------------------
__global__ __launch_bounds__(256) void tconvSq(const float* __restrict__ p0,
                                               const float* __restrict__ p1,
                                               u16* __restrict__ out)
{
    const int z = blockIdx.z;
    const float* ip = z == 0 ? p0 : p1;
    u16* op = out + (size_t)z * Ec * Ec;
    __shared__ float tile[32][33];
    const int r0 = blockIdx.x * 32, c0 = blockIdx.y * 32;
    const int ty = threadIdx.x >> 5, tx = threadIdx.x & 31;
#pragma unroll
    for (int i = ty; i < 32; i += 8) tile[i][tx] = ip[(size_t)(r0 + i) * Ec + c0 + tx];
    __syncthreads();
#pragma unroll
    for (int i = ty; i < 32; i += 8) op[(size_t)(c0 + i) * Ec + r0 + tx] = f2bf(tile[tx][i]);
}

// ---------------------------------------------------------------------------
// xPos trig tables: tabQ[s*64+ip] = (cos*scale, sin*scale), tabK = /scale.
// ---------------------------------------------------------------------------
__global__ __launch_bounds__(256) void trigk(float2* __restrict__ tabQ,
                                             float2* __restrict__ tabK)
{
    int t = blockIdx.x * 256 + threadIdx.x; // 2048*64
    int s = t >> 6, ip = t & 63;
    float sv = (2.f * (float)ip + 51.2f) * (1.f / 179.2f);
    float sc = exp2f(((float)s * (1.f / 512.f)) * log2f(sv));
    float freq = exp2f(-(float)ip * (13.287712379549449f / 64.f));
    float ang = (float)s * freq;
    float sn, cs;
    sincosf(ang, &sn, &cs);
    tabQ[t] = make_float2(cs * sc, sn * sc);
    tabK[t] = make_float2(cs / sc, sn / sc);
}

// ---------------------------------------------------------------------------
// Fused projection GEMM: one kernel computes Q|K|V|G = X x {Wq,Wk,Wv,Wg}^T.
// blockIdx.y: wsel = y>>3 picks weight/output/epilogue, n0 = (y&7)*128.
// 128x128 tile, BK=32, 4 waves, one-step register prefetch.
// ---------------------------------------------------------------------------
__global__ __launch_bounds__(256) void mgemm4(const u16* __restrict__ A,
                                              const u16* __restrict__ Ball,
                                              u16* __restrict__ Qo,
                                              u16* __restrict__ Ko,
                                              u16* __restrict__ Vo,
                                              u16* __restrict__ Go,
                                              const float2* __restrict__ tabQ,
                                              const float2* __restrict__ tabK)
{
    const int t = threadIdx.x;
    const int lane = t & 63, w = t >> 6;
    const int rl = lane & 15, hi = lane >> 4;
    const int r0 = blockIdx.x * 128;
    const int wsel = blockIdx.y >> 3;
    const int n0 = (blockIdx.y & 7) * 128;
    const u16* Bt = Ball + (size_t)wsel * Ec * Ec;

    __shared__ u16 As[128][40];
    __shared__ u16 Bs[128][40];

    f32x4 acc[2][8] = {};

    const int srow = t >> 1;
    const int sk   = (t & 1) * 16;
    const u16* Ap = A  + (size_t)(r0 + srow) * Ec + sk;
    const u16* Bp = Bt + (size_t)(n0 + srow) * Ec + sk;

    u16x8 a0 = *(const u16x8*)(Ap);
    u16x8 a1 = *(const u16x8*)(Ap + 8);
    u16x8 b0 = *(const u16x8*)(Bp);
    u16x8 b1 = *(const u16x8*)(Bp + 8);

    for (int k0 = 0; k0 < Ec; k0 += 32) {
        __syncthreads();
        *(u16x8*)&As[srow][sk]     = a0;
        *(u16x8*)&As[srow][sk + 8] = a1;
        *(u16x8*)&Bs[srow][sk]     = b0;
        *(u16x8*)&Bs[srow][sk + 8] = b1;
        __syncthreads();
        if (k0 + 32 < Ec) {
            a0 = *(const u16x8*)(Ap + k0 + 32);
            a1 = *(const u16x8*)(Ap + k0 + 40);
            b0 = *(const u16x8*)(Bp + k0 + 32);
            b1 = *(const u16x8*)(Bp + k0 + 40);
        }
        u16x8 bfr[8];
#pragma unroll
        for (int ct = 0; ct < 8; ++ct)
            bfr[ct] = *(const u16x8*)&Bs[ct * 16 + rl][hi * 8];
#pragma unroll
        for (int rt = 0; rt < 2; ++rt) {
            u16x8 afr = *(const u16x8*)&As[w * 32 + rt * 16 + rl][hi * 8];
#pragma unroll
            for (int ct = 0; ct < 8; ++ct)
                acc[rt][ct] = mfma16(afr, bfr[ct], acc[rt][ct]);
        }
    }

    u16* Cout = wsel == 0 ? Qo : wsel == 1 ? Ko : wsel == 2 ? Vo : Go;
    const float2* tab = wsel == 0 ? tabQ : tabK;

#pragma unroll
    for (int rt = 0; rt < 2; ++rt)
#pragma unroll
        for (int ct = 0; ct < 8; ++ct)
#pragma unroll
            for (int reg = 0; reg < 4; ++reg) {
                const int row = r0 + w * 32 + rt * 16 + hi * 4 + reg;
                const int col = n0 + ct * 16 + rl;
                float v = acc[rt][ct][reg];
                if (wsel <= 1) { // xPos rotate
                    float p = __shfl_xor(v, 1);
                    const float2 cssn = tab[(size_t)(row & 2047) * 64 + ((col >> 1) & 63)];
                    v = (lane & 1) ? (v * cssn.x + p * cssn.y)
                                   : (v * cssn.x - p * cssn.y);
                } else if (wsel == 3) { // silu
                    v = v / (1.f + expf(-v));
                }
                Cout[(size_t)row * Ec + col] = f2bf(v);
            }
}

// ---------------------------------------------------------------------------
// Retention + fused GroupNorm*gate.  Block = (64 Q-rows, one (b,h)), 4 waves.
// Grid 512: bh = id&15 (id%8 = h -> per-XCD K/V L2 residency); a = id>>4,
// rb = a<16 ? 31-a : a-16  (CU k co-hosts rb=31-a and rb=a: balanced).
// Q: all 64 rows register-resident (qf[4][4]).  QK: wave owns m-strip,
// S^T frag -> decay+mask -> Ss[n][m] (bf16).  SV: wave owns n-strip.
// K/V double-buffered in LDS: 2 barriers per chunk.
// ---------------------------------------------------------------------------
__global__ __launch_bounds__(256) void ret_gn(const u16* __restrict__ Q,
                                              const u16* __restrict__ K,
                                              const u16* __restrict__ V,
                                              const u16* __restrict__ G,
                                              const float* __restrict__ gw,
                                              const float* __restrict__ gbias,
                                              u16* __restrict__ Z)
{
    const int t = threadIdx.x, lane = t & 63, w = t >> 6;
    const int rl = lane & 15, hi = lane >> 4;
    const int id = blockIdx.x;
    const int bh = id & 15;
    const int a  = id >> 4;
    const int rb = (a < 16) ? (31 - a) : (a - 16);
    const int b = bh >> 3, h = bh & 7;

    __shared__ u16 Ks[2][64][136];
    __shared__ u16 Vt[2][128][68]; // V transposed: Vt[buf][d][m]
    __shared__ u16 Ss[64][72];     // S[n][m]

    const float lga = -3.4657359027997265f; // log(1/32)
    const float lgb = -6.2383246250395075f; // log(1/512)
    const float gamma = 1.f - expf(lga + (float)h * (lgb - lga) * (1.f / 7.f));
    const float lg2 = log2f(gamma);

    int c_lo = 0;
    {
        float cut = 9.2103404f / (-logf(gamma)); // weight >= ~1e-4
        int mmin = rb * 64 - (int)cut;
        if (mmin > 0) c_lo = mmin >> 6;
    }

    // per-lane staging geometry
    const int ki = t >> 2,        kq = (t & 3) * 32;  // K: row, 32-elem quarter
    const int vm4 = (t & 15) * 4, vd = (t >> 4) * 8;  // V: 4 rows, 8-d segment
    const u16* Kg0 = K + (size_t)(b * Sc) * Ec + h * Dc;
    const u16* Vg0 = V + (size_t)(b * Sc) * Ec + h * Dc;

    // ---- issue first K/V chunk loads (independent of LDS) ----
    u16x8 kreg[4], vreg[4];
    {
        const u16* Kg = Kg0 + (size_t)(c_lo * 64 + ki) * Ec + kq;
#pragma unroll
        for (int r = 0; r < 4; ++r) kreg[r] = *(const u16x8*)(Kg + r * 8);
        const u16* Vg = Vg0 + (size_t)(c_lo * 64 + vm4) * Ec + vd;
#pragma unroll
        for (int r = 0; r < 4; ++r) vreg[r] = *(const u16x8*)(Vg + (size_t)r * Ec);
    }

    // ---- stage Q through Ks[0]; every wave pulls ALL 64 rows to registers ----
    {
        const int i = t >> 2, q = (t & 3) * 32;
        const u16* Qg = Q + (size_t)(b * Sc + rb * 64 + i) * Ec + h * Dc + q;
        u16x8 v0 = *(const u16x8*)(Qg);
        u16x8 v1 = *(const u16x8*)(Qg + 8);
        u16x8 v2 = *(const u16x8*)(Qg + 16);
        u16x8 v3 = *(const u16x8*)(Qg + 24);
        *(u16x8*)&Ks[0][i][q]      = v0;
        *(u16x8*)&Ks[0][i][q + 8]  = v1;
        *(u16x8*)&Ks[0][i][q + 16] = v2;
        *(u16x8*)&Ks[0][i][q + 24] = v3;
    }
    __syncthreads();
    u16x8 qf[4][4];
#pragma unroll
    for (int nt = 0; nt < 4; ++nt)
#pragma unroll
        for (int ks = 0; ks < 4; ++ks)
            qf[nt][ks] = *(const u16x8*)&Ks[0][nt * 16 + rl][ks * 32 + hi * 8];
    __syncthreads(); // Q frags read before chunk loop overwrites Ks[0]

    // decay: wgt(n,m) = nf[nt] * mf[reg]
    float mf[4];
#pragma unroll
    for (int reg = 0; reg < 4; ++reg)
        mf[reg] = exp2f(-lg2 * (float)(w * 16 + hi * 4 + reg));
    float nf[4];
#pragma unroll
    for (int nt = 0; nt < 4; ++nt)
        nf[nt] = exp2f(lg2 * (float)((rb - c_lo) * 64 + nt * 16 + rl));
    const float ginv64 = exp2f(-lg2 * 64.f);

    f32x4 yacc[8] = {};

    for (int c = c_lo; c <= rb; ++c) {
        const int cur = c & 1;
        // regs -> LDS (double-buffered: no barrier needed before write)
#pragma unroll
        for (int r = 0; r < 4; ++r)
            *(u16x8*)&Ks[cur][ki][kq + r * 8] = kreg[r];
#pragma unroll
        for (int j = 0; j < 8; ++j) {
            u16x4 p;
            p[0] = vreg[0][j]; p[1] = vreg[1][j]; p[2] = vreg[2][j]; p[3] = vreg[3][j];
            *(u16x4*)&Vt[cur][vd + j][vm4] = p;
        }
        __syncthreads();
        if (c < rb) { // prefetch next chunk under compute
            const u16* Kg = Kg0 + (size_t)((c + 1) * 64 + ki) * Ec + kq;
#pragma unroll
            for (int r = 0; r < 4; ++r) kreg[r] = *(const u16x8*)(Kg + r * 8);
            const u16* Vg = Vg0 + (size_t)((c + 1) * 64 + vm4) * Ec + vd;
#pragma unroll
            for (int r = 0; r < 4; ++r) vreg[r] = *(const u16x8*)(Vg + (size_t)r * Ec);
        }

        // QK^T: wave owns m-strip [w*16, w*16+16); S^T frag -> Ss[n][m]
        __builtin_amdgcn_s_setprio(1);
        u16x8 kf[4];
#pragma unroll
        for (int ks = 0; ks < 4; ++ks)
            kf[ks] = *(const u16x8*)&Ks[cur][w * 16 + rl][ks * 32 + hi * 8];
#pragma unroll
        for (int nt = 0; nt < 4; ++nt) {
            f32x4 s = {};
#pragma unroll
            for (int ks = 0; ks < 4; ++ks)
                s = mfma16(kf[ks], qf[nt][ks], s);
            // lane holds S[n = nt*16+rl][m = w*16+hi*4+reg], reg=0..3
            u16x4 pk;
#pragma unroll
            for (int reg = 0; reg < 4; ++reg) {
                float wgt = nf[nt] * mf[reg];
                if (c == rb && (w * 16 + hi * 4 + reg) > (nt * 16 + rl)) wgt = 0.f;
                pk[reg] = f2bf(s[reg] * wgt);
            }
            *(u16x4*)&Ss[nt * 16 + rl][w * 16 + hi * 4] = pk;
        }
        __builtin_amdgcn_s_setprio(0);
        __syncthreads();

        // Y += S V: wave owns n-strip [w*16, w*16+16)
        u16x8 sf0 = *(const u16x8*)&Ss[w * 16 + rl][hi * 8];
        u16x8 sf1 = *(const u16x8*)&Ss[w * 16 + rl][32 + hi * 8];
        __builtin_amdgcn_s_setprio(1);
#pragma unroll
        for (int ct = 0; ct < 8; ++ct) {
            u16x8 vf0 = *(const u16x8*)&Vt[cur][ct * 16 + rl][hi * 8];
            u16x8 vf1 = *(const u16x8*)&Vt[cur][ct * 16 + rl][32 + hi * 8];
            yacc[ct] = mfma16(sf0, vf0, yacc[ct]);
            yacc[ct] = mfma16(sf1, vf1, yacc[ct]);
        }
        __builtin_amdgcn_s_setprio(0);
#pragma unroll
        for (int nt = 0; nt < 4; ++nt) nf[nt] *= ginv64;
    }

    // ---- fused GroupNorm * gate epilogue ----
#pragma unroll
    for (int reg = 0; reg < 4; ++reg) {
        const int nloc = w * 16 + hi * 4 + reg;
        const size_t row = (size_t)(b * Sc + rb * 64 + nloc);
        float s = 0.f, sq = 0.f;
#pragma unroll
        for (int ct = 0; ct < 8; ++ct) {
            float v = yacc[ct][reg];
            s += v; sq += v * v;
        }
#pragma unroll
        for (int o = 1; o < 16; o <<= 1) {
            s  += __shfl_xor(s, o, 64);
            sq += __shfl_xor(sq, o, 64);
        }
        const float mu  = s * (1.f / 128.f);
        const float var = sq * (1.f / 128.f) - mu * mu;
        const float inv = rsqrtf(var + 1e-5f);
#pragma unroll
        for (int ct = 0; ct < 8; ++ct) {
            const int col = h * Dc + ct * 16 + rl;
            const float gate = bf2f(G[row * Ec + col]);
            const float z = ((yacc[ct][reg] - mu) * inv * gw[col] + gbias[col]) * gate;
            Z[row * Ec + col] = f2bf(z);
        }
    }
}

// ---------------------------------------------------------------------------
// Final GEMM: out(f32) = Z x WoT^T.  Same structure as mgemm4, plain epilogue.
// ---------------------------------------------------------------------------
__global__ __launch_bounds__(256) void mgemmO(const u16* __restrict__ A,
                                              const u16* __restrict__ Bt,
                                              float* __restrict__ Cout)
{
    const int t = threadIdx.x;
    const int lane = t & 63, w = t >> 6;
    const int rl = lane & 15, hi = lane >> 4;
    const int r0 = blockIdx.x * 128;
    const int n0 = blockIdx.y * 128;

    __shared__ u16 As[128][40];
    __shared__ u16 Bs[128][40];

    f32x4 acc[2][8] = {};

    const int srow = t >> 1;
    const int sk   = (t & 1) * 16;
    const u16* Ap = A  + (size_t)(r0 + srow) * Ec + sk;
    const u16* Bp = Bt + (size_t)(n0 + srow) * Ec + sk;

    u16x8 a0 = *(const u16x8*)(Ap);
    u16x8 a1 = *(const u16x8*)(Ap + 8);
    u16x8 b0 = *(const u16x8*)(Bp);
    u16x8 b1 = *(const u16x8*)(Bp + 8);

    for (int k0 = 0; k0 < Ec; k0 += 32) {
        __syncthreads();
        *(u16x8*)&As[srow][sk]     = a0;
        *(u16x8*)&As[srow][sk + 8] = a1;
        *(u16x8*)&Bs[srow][sk]     = b0;
        *(u16x8*)&Bs[srow][sk + 8] = b1;
        __syncthreads();
        if (k0 + 32 < Ec) {
            a0 = *(const u16x8*)(Ap + k0 + 32);
            a1 = *(const u16x8*)(Ap + k0 + 40);
            b0 = *(const u16x8*)(Bp + k0 + 32);
            b1 = *(const u16x8*)(Bp + k0 + 40);
        }
        u16x8 bfr[8];
#pragma unroll
        for (int ct = 0; ct < 8; ++ct)
            bfr[ct] = *(const u16x8*)&Bs[ct * 16 + rl][hi * 8];
#pragma unroll
        for (int rt = 0; rt < 2; ++rt) {
            u16x8 afr = *(const u16x8*)&As[w * 32 + rt * 16 + rl][hi * 8];
#pragma unroll
            for (int ct = 0; ct < 8; ++ct)
                acc[rt][ct] = mfma16(afr, bfr[ct], acc[rt][ct]);
        }
    }

#pragma unroll
    for (int rt = 0; rt < 2; ++rt)
#pragma unroll
        for (int ct = 0; ct < 8; ++ct)
#pragma unroll
            for (int reg = 0; reg < 4; ++reg) {
                const int row = r0 + w * 32 + rt * 16 + hi * 4 + reg;
                const int col = n0 + ct * 16 + rl;
                Cout[(size_t)row * Ec + col] = acc[rt][ct][reg];
            }
}

} // anonymous namespace

extern "C" void kernel_launch(void* const* d_in, const int* in_sizes, int n_in,
                              void* d_out, int out_size, void* d_ws, size_t ws_size,
                              hipStream_t stream)
{
    const float* X    = (const float*)d_in[0];
    const float* W_Q  = (const float*)d_in[1];
    const float* W_K  = (const float*)d_in[2];
    const float* W_V  = (const float*)d_in[3];
    const float* W_G  = (const float*)d_in[4];
    const float* W_O  = (const float*)d_in[5];
    const float* gw   = (const float*)d_in[6];
    const float* gb   = (const float*)d_in[7];

    char* ws = (char*)d_ws;
    const size_t NX = (size_t)Mc * Ec;          // 4 Mi elements
    u16*    Xb   = (u16*)ws;                ws += NX * 2;              // 8 MB
    u16*    WqT  = (u16*)ws;                ws += (size_t)Ec * Ec * 2; // 2 MB (x4, contiguous)
    u16*    WkT  = (u16*)ws;                ws += (size_t)Ec * Ec * 2;
    u16*    WvT  = (u16*)ws;                ws += (size_t)Ec * Ec * 2;
    u16*    WgT  = (u16*)ws;                ws += (size_t)Ec * Ec * 2;
    u16*    WoT  = (u16*)ws;                ws += (size_t)Ec * Ec * 2;
    float2* tabQ = (float2*)ws;             ws += (size_t)Sc * 64 * sizeof(float2); // 1 MB
    float2* tabK = (float2*)ws;             ws += (size_t)Sc * 64 * sizeof(float2);
    u16*    Qb   = (u16*)ws;                ws += NX * 2;              // 8 MB
    u16*    Kb   = (u16*)ws;                ws += NX * 2;
    u16*    Vb   = (u16*)ws;                ws += NX * 2;
    u16*    Gb   = (u16*)ws;                ws += NX * 2;
    u16*    Zb   = (u16*)ws;                ws += NX * 2;
    (void)WkT; (void)WvT; (void)WgT;

    dim3 blk(256);
    convX<<<dim3((int)(NX / 8 / 256)), blk, 0, stream>>>(X, Xb, (int)(NX / 8));
    tconvH<<<dim3(32, 4, 24), blk, 0, stream>>>(W_Q, W_K, W_V, WqT);
    tconvSq<<<dim3(32, 32, 2), blk, 0, stream>>>(W_G, W_O, WgT);
    trigk<<<dim3(Sc * 64 / 256), blk, 0, stream>>>(tabQ, tabK);

    mgemm4<<<dim3(Mc / 128, 32), blk, 0, stream>>>(Xb, WqT, Qb, Kb, Vb, Gb, tabQ, tabK);

    ret_gn<<<dim3(512), blk, 0, stream>>>(Qb, Kb, Vb, Gb, gw, gb, Zb);

    mgemmO<<<dim3(Mc / 128, Ec / 128), blk, 0, stream>>>(Zb, WoT, (float*)d_out);
}

// Round 5
// 157.418 us; speedup vs baseline: 10.0812x; 1.0025x over previous
//
#include <hip/hip_runtime.h>
#include <hip/hip_bf16.h>
#include <math.h>

namespace {

constexpr int Bc = 2;
constexpr int Sc = 2048;
constexpr int Ec = 1024;
constexpr int Hc = 8;
constexpr int Dc = 128;
constexpr int Mc = Bc * Sc; // 4096

typedef unsigned short u16;
typedef u16    u16x8  __attribute__((ext_vector_type(8)));
typedef u16    u16x4  __attribute__((ext_vector_type(4)));
typedef __bf16 bf16x8 __attribute__((ext_vector_type(8)));
typedef float  f32x4  __attribute__((ext_vector_type(4)));

static __device__ inline bf16x8 asbf(u16x8 v) { return __builtin_bit_cast(bf16x8, v); }

static __device__ inline f32x4 mfma16(u16x8 a, u16x8 b, f32x4 c) {
    return __builtin_amdgcn_mfma_f32_16x16x32_bf16(asbf(a), asbf(b), c, 0, 0, 0);
}

static __device__ inline u16 f2bf(float f) {
    unsigned u = __builtin_bit_cast(unsigned, f);
    return (u16)((u + 0x7fffu + ((u >> 16) & 1u)) >> 16);
}
static __device__ inline float bf2f(u16 h) {
    unsigned u = ((unsigned)h) << 16;
    return __builtin_bit_cast(float, u);
}

// Async global->LDS DMA, 16B per lane.  LDS dest must be wave-uniform base;
// HW writes lane l at dest + l*16B.  (m97 pattern, guide §5.)
static __device__ inline void gload16(const u16* g, u16* l) {
    __builtin_amdgcn_global_load_lds(
        (__attribute__((address_space(1))) void*)const_cast<u16*>(g),
        (__attribute__((address_space(3))) void*)l,
        16, 0, 0);
}

// ---------------------------------------------------------------------------
// X f32 -> bf16, flat.
// ---------------------------------------------------------------------------
__global__ __launch_bounds__(256) void convX(const float* __restrict__ in,
                                             u16* __restrict__ out, int n8)
{
    int i = blockIdx.x * 256 + threadIdx.x;
    if (i >= n8) return;
    float4 a = *(const float4*)(in + (size_t)i * 8);
    float4 b = *(const float4*)(in + (size_t)i * 8 + 4);
    u16x8 o;
    o[0] = f2bf(a.x); o[1] = f2bf(a.y); o[2] = f2bf(a.z); o[3] = f2bf(a.w);
    o[4] = f2bf(b.x); o[5] = f2bf(b.y); o[6] = f2bf(b.z); o[7] = f2bf(b.w);
    *(u16x8*)(out + (size_t)i * 8) = o;
}

// ---------------------------------------------------------------------------
// Head-weight transpose+convert: 3 sources [8][1024][128] -> out[z][128][1024].
// ---------------------------------------------------------------------------
__global__ __launch_bounds__(256) void tconvH(const float* __restrict__ p0,
                                              const float* __restrict__ p1,
                                              const float* __restrict__ p2,
                                              u16* __restrict__ out)
{
    const int z = blockIdx.z;
    const float* ip = (z < 8 ? p0 : z < 16 ? p1 : p2) + (size_t)(z & 7) * Ec * Dc;
    u16* op = out + (size_t)z * Dc * Ec;
    __shared__ float tile[32][33];
    const int r0 = blockIdx.x * 32, c0 = blockIdx.y * 32;
    const int ty = threadIdx.x >> 5, tx = threadIdx.x & 31;
#pragma unroll
    for (int i = ty; i < 32; i += 8) tile[i][tx] = ip[(size_t)(r0 + i) * Dc + c0 + tx];
    __syncthreads();
#pragma unroll
    for (int i = ty; i < 32; i += 8) op[(size_t)(c0 + i) * Ec + r0 + tx] = f2bf(tile[tx][i]);
}

// ---------------------------------------------------------------------------
// Square-weight transpose+convert: 2 sources [1024][1024] -> out[z][1024][1024].
// ---------------------------------------------------------------------------
__global__ __launch_bounds__(256) void tconvSq(const float* __restrict__ p0,
                                               const float* __restrict__ p1,
                                               u16* __restrict__ out)
{
    const int z = blockIdx.z;
    const float* ip = z == 0 ? p0 : p1;
    u16* op = out + (size_t)z * Ec * Ec;
    __shared__ float tile[32][33];
    const int r0 = blockIdx.x * 32, c0 = blockIdx.y * 32;
    const int ty = threadIdx.x >> 5, tx = threadIdx.x & 31;
#pragma unroll
    for (int i = ty; i < 32; i += 8) tile[i][tx] = ip[(size_t)(r0 + i) * Ec + c0 + tx];
    __syncthreads();
#pragma unroll
    for (int i = ty; i < 32; i += 8) op[(size_t)(c0 + i) * Ec + r0 + tx] = f2bf(tile[tx][i]);
}

// ---------------------------------------------------------------------------
// xPos trig tables: tabQ[s*64+ip] = (cos*scale, sin*scale), tabK = /scale.
// ---------------------------------------------------------------------------
__global__ __launch_bounds__(256) void trigk(float2* __restrict__ tabQ,
                                             float2* __restrict__ tabK)
{
    int t = blockIdx.x * 256 + threadIdx.x; // 2048*64
    int s = t >> 6, ip = t & 63;
    float sv = (2.f * (float)ip + 51.2f) * (1.f / 179.2f);
    float sc = exp2f(((float)s * (1.f / 512.f)) * log2f(sv));
    float freq = exp2f(-(float)ip * (13.287712379549449f / 64.f));
    float ang = (float)s * freq;
    float sn, cs;
    sincosf(ang, &sn, &cs);
    tabQ[t] = make_float2(cs * sc, sn * sc);
    tabK[t] = make_float2(cs / sc, sn / sc);
}

// ---------------------------------------------------------------------------
// Shared GEMM core (m97 structure): 128x128 tile, BK=32, 4 waves, linear LDS
// [128][32] u16, global_load_lds dwordx4 staging, 2 barriers per K-step.
// Each wave DMAs rows [w*32, w*32+32) of both tiles (2 x 1KB per tile).
// ---------------------------------------------------------------------------
static __device__ inline void gemm_core(const u16* __restrict__ A,
                                        const u16* __restrict__ Bt,
                                        int r0, int n0, int lane, int w,
                                        u16* AsF, u16* BsF, f32x4 acc[2][8])
{
    const int rl = lane & 15, hi = lane >> 4;
    // per-lane global sources for this wave's DMA chunk (16 rows per instr)
    const u16* Ag = A  + (size_t)(r0 + w * 32 + (lane >> 2)) * Ec + (lane & 3) * 8;
    const u16* Bg = Bt + (size_t)(n0 + w * 32 + (lane >> 2)) * Ec + (lane & 3) * 8;
    u16* lA = AsF + w * 32 * 32;  // wave-uniform LDS dest
    u16* lB = BsF + w * 32 * 32;

    for (int k0 = 0; k0 < Ec; k0 += 32) {
        __syncthreads();  // prior K-step's ds_reads complete
        gload16(Ag + k0,                      lA);
        gload16(Ag + (size_t)16 * Ec + k0,    lA + 16 * 32);
        gload16(Bg + k0,                      lB);
        gload16(Bg + (size_t)16 * Ec + k0,    lB + 16 * 32);
        __syncthreads();  // DMA drained (vmcnt(0) before barrier)

        u16x8 bfr[8];
#pragma unroll
        for (int ct = 0; ct < 8; ++ct)
            bfr[ct] = *(const u16x8*)&BsF[(ct * 16 + rl) * 32 + hi * 8];
#pragma unroll
        for (int rt = 0; rt < 2; ++rt) {
            u16x8 afr = *(const u16x8*)&AsF[(w * 32 + rt * 16 + rl) * 32 + hi * 8];
#pragma unroll
            for (int ct = 0; ct < 8; ++ct)
                acc[rt][ct] = mfma16(afr, bfr[ct], acc[rt][ct]);
        }
    }
}

// ---------------------------------------------------------------------------
// Fused projection GEMM: Q|K|V|G = X x {Wq,Wk,Wv,Wg}^T.
// blockIdx.y: wsel = y>>3 picks weight/output/epilogue, n0 = (y&7)*128.
// ---------------------------------------------------------------------------
__global__ __launch_bounds__(256) void mgemm4(const u16* __restrict__ A,
                                              const u16* __restrict__ Ball,
                                              u16* __restrict__ Qo,
                                              u16* __restrict__ Ko,
                                              u16* __restrict__ Vo,
                                              u16* __restrict__ Go,
                                              const float2* __restrict__ tabQ,
                                              const float2* __restrict__ tabK)
{
    const int t = threadIdx.x;
    const int lane = t & 63, w = t >> 6;
    const int rl = lane & 15, hi = lane >> 4;
    const int r0 = blockIdx.x * 128;
    const int wsel = blockIdx.y >> 3;
    const int n0 = (blockIdx.y & 7) * 128;
    const u16* Bt = Ball + (size_t)wsel * Ec * Ec;

    __shared__ u16 As[128 * 32];
    __shared__ u16 Bs[128 * 32];

    f32x4 acc[2][8] = {};
    gemm_core(A, Bt, r0, n0, lane, w, As, Bs, acc);

    u16* Cout = wsel == 0 ? Qo : wsel == 1 ? Ko : wsel == 2 ? Vo : Go;
    const float2* tab = wsel == 0 ? tabQ : tabK;

#pragma unroll
    for (int rt = 0; rt < 2; ++rt)
#pragma unroll
        for (int ct = 0; ct < 8; ++ct)
#pragma unroll
            for (int reg = 0; reg < 4; ++reg) {
                const int row = r0 + w * 32 + rt * 16 + hi * 4 + reg;
                const int col = n0 + ct * 16 + rl;
                float v = acc[rt][ct][reg];
                if (wsel <= 1) { // xPos rotate
                    float p = __shfl_xor(v, 1);
                    const float2 cssn = tab[(size_t)(row & 2047) * 64 + ((col >> 1) & 63)];
                    v = (lane & 1) ? (v * cssn.x + p * cssn.y)
                                   : (v * cssn.x - p * cssn.y);
                } else if (wsel == 3) { // silu
                    v = v / (1.f + expf(-v));
                }
                Cout[(size_t)row * Ec + col] = f2bf(v);
            }
}

// ---------------------------------------------------------------------------
// Final GEMM: out(f32) = Z x WoT^T.
// ---------------------------------------------------------------------------
__global__ __launch_bounds__(256) void mgemmO(const u16* __restrict__ A,
                                              const u16* __restrict__ Bt,
                                              float* __restrict__ Cout)
{
    const int t = threadIdx.x;
    const int lane = t & 63, w = t >> 6;
    const int rl = lane & 15, hi = lane >> 4;
    const int r0 = blockIdx.x * 128;
    const int n0 = blockIdx.y * 128;

    __shared__ u16 As[128 * 32];
    __shared__ u16 Bs[128 * 32];

    f32x4 acc[2][8] = {};
    gemm_core(A, Bt, r0, n0, lane, w, As, Bs, acc);

#pragma unroll
    for (int rt = 0; rt < 2; ++rt)
#pragma unroll
        for (int ct = 0; ct < 8; ++ct)
#pragma unroll
            for (int reg = 0; reg < 4; ++reg) {
                const int row = r0 + w * 32 + rt * 16 + hi * 4 + reg;
                const int col = n0 + ct * 16 + rl;
                Cout[(size_t)row * Ec + col] = acc[rt][ct][reg];
            }
}

// ---------------------------------------------------------------------------
// Retention + fused GroupNorm*gate.  Block = (64 Q-rows, one (b,h)), 4 waves.
// Grid 512: bh = id&15 (id%8 = h -> per-XCD K/V L2 residency); a = id>>4,
// rb = a<16 ? 31-a : a-16  (CU k co-hosts rb=31-a and rb=a: balanced).
// Q: all 64 rows register-resident (qf[4][4]).  QK: wave owns m-strip,
// S^T frag -> decay+mask -> Ss[n][m] (bf16).  SV: wave owns n-strip.
// K/V double-buffered in LDS: 2 barriers per chunk.
// ---------------------------------------------------------------------------
__global__ __launch_bounds__(256) void ret_gn(const u16* __restrict__ Q,
                                              const u16* __restrict__ K,
                                              const u16* __restrict__ V,
                                              const u16* __restrict__ G,
                                              const float* __restrict__ gw,
                                              const float* __restrict__ gbias,
                                              u16* __restrict__ Z)
{
    const int t = threadIdx.x, lane = t & 63, w = t >> 6;
    const int rl = lane & 15, hi = lane >> 4;
    const int id = blockIdx.x;
    const int bh = id & 15;
    const int a  = id >> 4;
    const int rb = (a < 16) ? (31 - a) : (a - 16);
    const int b = bh >> 3, h = bh & 7;

    __shared__ u16 Ks[2][64][136];
    __shared__ u16 Vt[2][128][68]; // V transposed: Vt[buf][d][m]
    __shared__ u16 Ss[64][72];     // S[n][m]

    const float lga = -3.4657359027997265f; // log(1/32)
    const float lgb = -6.2383246250395075f; // log(1/512)
    const float gamma = 1.f - expf(lga + (float)h * (lgb - lga) * (1.f / 7.f));
    const float lg2 = log2f(gamma);

    int c_lo = 0;
    {
        float cut = 9.2103404f / (-logf(gamma)); // weight >= ~1e-4
        int mmin = rb * 64 - (int)cut;
        if (mmin > 0) c_lo = mmin >> 6;
    }

    // per-lane staging geometry
    const int ki = t >> 2,        kq = (t & 3) * 32;  // K: row, 32-elem quarter
    const int vm4 = (t & 15) * 4, vd = (t >> 4) * 8;  // V: 4 rows, 8-d segment
    const u16* Kg0 = K + (size_t)(b * Sc) * Ec + h * Dc;
    const u16* Vg0 = V + (size_t)(b * Sc) * Ec + h * Dc;

    // ---- issue first K/V chunk loads (independent of LDS) ----
    u16x8 kreg[4], vreg[4];
    {
        const u16* Kg = Kg0 + (size_t)(c_lo * 64 + ki) * Ec + kq;
#pragma unroll
        for (int r = 0; r < 4; ++r) kreg[r] = *(const u16x8*)(Kg + r * 8);
        const u16* Vg = Vg0 + (size_t)(c_lo * 64 + vm4) * Ec + vd;
#pragma unroll
        for (int r = 0; r < 4; ++r) vreg[r] = *(const u16x8*)(Vg + (size_t)r * Ec);
    }

    // ---- stage Q through Ks[0]; every wave pulls ALL 64 rows to registers ----
    {
        const int i = t >> 2, q = (t & 3) * 32;
        const u16* Qg = Q + (size_t)(b * Sc + rb * 64 + i) * Ec + h * Dc + q;
        u16x8 v0 = *(const u16x8*)(Qg);
        u16x8 v1 = *(const u16x8*)(Qg + 8);
        u16x8 v2 = *(const u16x8*)(Qg + 16);
        u16x8 v3 = *(const u16x8*)(Qg + 24);
        *(u16x8*)&Ks[0][i][q]      = v0;
        *(u16x8*)&Ks[0][i][q + 8]  = v1;
        *(u16x8*)&Ks[0][i][q + 16] = v2;
        *(u16x8*)&Ks[0][i][q + 24] = v3;
    }
    __syncthreads();
    u16x8 qf[4][4];
#pragma unroll
    for (int nt = 0; nt < 4; ++nt)
#pragma unroll
        for (int ks = 0; ks < 4; ++ks)
            qf[nt][ks] = *(const u16x8*)&Ks[0][nt * 16 + rl][ks * 32 + hi * 8];
    __syncthreads(); // Q frags read before chunk loop overwrites Ks[0]

    // decay: wgt(n,m) = nf[nt] * mf[reg]
    float mf[4];
#pragma unroll
    for (int reg = 0; reg < 4; ++reg)
        mf[reg] = exp2f(-lg2 * (float)(w * 16 + hi * 4 + reg));
    float nf[4];
#pragma unroll
    for (int nt = 0; nt < 4; ++nt)
        nf[nt] = exp2f(lg2 * (float)((rb - c_lo) * 64 + nt * 16 + rl));
    const float ginv64 = exp2f(-lg2 * 64.f);

    f32x4 yacc[8] = {};

    for (int c = c_lo; c <= rb; ++c) {
        const int cur = c & 1;
        // regs -> LDS (double-buffered: no barrier needed before write)
#pragma unroll
        for (int r = 0; r < 4; ++r)
            *(u16x8*)&Ks[cur][ki][kq + r * 8] = kreg[r];
#pragma unroll
        for (int j = 0; j < 8; ++j) {
            u16x4 p;
            p[0] = vreg[0][j]; p[1] = vreg[1][j]; p[2] = vreg[2][j]; p[3] = vreg[3][j];
            *(u16x4*)&Vt[cur][vd + j][vm4] = p;
        }
        __syncthreads();
        if (c < rb) { // prefetch next chunk under compute
            const u16* Kg = Kg0 + (size_t)((c + 1) * 64 + ki) * Ec + kq;
#pragma unroll
            for (int r = 0; r < 4; ++r) kreg[r] = *(const u16x8*)(Kg + r * 8);
            const u16* Vg = Vg0 + (size_t)((c + 1) * 64 + vm4) * Ec + vd;
#pragma unroll
            for (int r = 0; r < 4; ++r) vreg[r] = *(const u16x8*)(Vg + (size_t)r * Ec);
        }

        // QK^T: wave owns m-strip [w*16, w*16+16); S^T frag -> Ss[n][m]
        __builtin_amdgcn_s_setprio(1);
        u16x8 kf[4];
#pragma unroll
        for (int ks = 0; ks < 4; ++ks)
            kf[ks] = *(const u16x8*)&Ks[cur][w * 16 + rl][ks * 32 + hi * 8];
#pragma unroll
        for (int nt = 0; nt < 4; ++nt) {
            f32x4 s = {};
#pragma unroll
            for (int ks = 0; ks < 4; ++ks)
                s = mfma16(kf[ks], qf[nt][ks], s);
            // lane holds S[n = nt*16+rl][m = w*16+hi*4+reg], reg=0..3
            u16x4 pk;
#pragma unroll
            for (int reg = 0; reg < 4; ++reg) {
                float wgt = nf[nt] * mf[reg];
                if (c == rb && (w * 16 + hi * 4 + reg) > (nt * 16 + rl)) wgt = 0.f;
                pk[reg] = f2bf(s[reg] * wgt);
            }
            *(u16x4*)&Ss[nt * 16 + rl][w * 16 + hi * 4] = pk;
        }
        __builtin_amdgcn_s_setprio(0);
        __syncthreads();

        // Y += S V: wave owns n-strip [w*16, w*16+16)
        u16x8 sf0 = *(const u16x8*)&Ss[w * 16 + rl][hi * 8];
        u16x8 sf1 = *(const u16x8*)&Ss[w * 16 + rl][32 + hi * 8];
        __builtin_amdgcn_s_setprio(1);
#pragma unroll
        for (int ct = 0; ct < 8; ++ct) {
            u16x8 vf0 = *(const u16x8*)&Vt[cur][ct * 16 + rl][hi * 8];
            u16x8 vf1 = *(const u16x8*)&Vt[cur][ct * 16 + rl][32 + hi * 8];
            yacc[ct] = mfma16(sf0, vf0, yacc[ct]);
            yacc[ct] = mfma16(sf1, vf1, yacc[ct]);
        }
        __builtin_amdgcn_s_setprio(0);
#pragma unroll
        for (int nt = 0; nt < 4; ++nt) nf[nt] *= ginv64;
    }

    // ---- fused GroupNorm * gate epilogue ----
#pragma unroll
    for (int reg = 0; reg < 4; ++reg) {
        const int nloc = w * 16 + hi * 4 + reg;
        const size_t row = (size_t)(b * Sc + rb * 64 + nloc);
        float s = 0.f, sq = 0.f;
#pragma unroll
        for (int ct = 0; ct < 8; ++ct) {
            float v = yacc[ct][reg];
            s += v; sq += v * v;
        }
#pragma unroll
        for (int o = 1; o < 16; o <<= 1) {
            s  += __shfl_xor(s, o, 64);
            sq += __shfl_xor(sq, o, 64);
        }
        const float mu  = s * (1.f / 128.f);
        const float var = sq * (1.f / 128.f) - mu * mu;
        const float inv = rsqrtf(var + 1e-5f);
#pragma unroll
        for (int ct = 0; ct < 8; ++ct) {
            const int col = h * Dc + ct * 16 + rl;
            const float gate = bf2f(G[row * Ec + col]);
            const float z = ((yacc[ct][reg] - mu) * inv * gw[col] + gbias[col]) * gate;
            Z[row * Ec + col] = f2bf(z);
        }
    }
}

} // anonymous namespace

extern "C" void kernel_launch(void* const* d_in, const int* in_sizes, int n_in,
                              void* d_out, int out_size, void* d_ws, size_t ws_size,
                              hipStream_t stream)
{
    const float* X    = (const float*)d_in[0];
    const float* W_Q  = (const float*)d_in[1];
    const float* W_K  = (const float*)d_in[2];
    const float* W_V  = (const float*)d_in[3];
    const float* W_G  = (const float*)d_in[4];
    const float* W_O  = (const float*)d_in[5];
    const float* gw   = (const float*)d_in[6];
    const float* gb   = (const float*)d_in[7];

    char* ws = (char*)d_ws;
    const size_t NX = (size_t)Mc * Ec;          // 4 Mi elements
    u16*    Xb   = (u16*)ws;                ws += NX * 2;              // 8 MB
    u16*    WqT  = (u16*)ws;                ws += (size_t)Ec * Ec * 2; // 2 MB (x4, contiguous)
    u16*    WkT  = (u16*)ws;                ws += (size_t)Ec * Ec * 2;
    u16*    WvT  = (u16*)ws;                ws += (size_t)Ec * Ec * 2;
    u16*    WgT  = (u16*)ws;                ws += (size_t)Ec * Ec * 2;
    u16*    WoT  = (u16*)ws;                ws += (size_t)Ec * Ec * 2;
    float2* tabQ = (float2*)ws;             ws += (size_t)Sc * 64 * sizeof(float2); // 1 MB
    float2* tabK = (float2*)ws;             ws += (size_t)Sc * 64 * sizeof(float2);
    u16*    Qb   = (u16*)ws;                ws += NX * 2;              // 8 MB
    u16*    Kb   = (u16*)ws;                ws += NX * 2;
    u16*    Vb   = (u16*)ws;                ws += NX * 2;
    u16*    Gb   = (u16*)ws;                ws += NX * 2;
    u16*    Zb   = (u16*)ws;                ws += NX * 2;
    (void)WkT; (void)WvT; (void)WgT;

    dim3 blk(256);
    convX<<<dim3((int)(NX / 8 / 256)), blk, 0, stream>>>(X, Xb, (int)(NX / 8));
    tconvH<<<dim3(32, 4, 24), blk, 0, stream>>>(W_Q, W_K, W_V, WqT);
    tconvSq<<<dim3(32, 32, 2), blk, 0, stream>>>(W_G, W_O, WgT);
    trigk<<<dim3(Sc * 64 / 256), blk, 0, stream>>>(tabQ, tabK);

    mgemm4<<<dim3(Mc / 128, 32), blk, 0, stream>>>(Xb, WqT, Qb, Kb, Vb, Gb, tabQ, tabK);

    ret_gn<<<dim3(512), blk, 0, stream>>>(Qb, Kb, Vb, Gb, gw, gb, Zb);

    mgemmO<<<dim3(Mc / 128, Ec / 128), blk, 0, stream>>>(Zb, WoT, (float*)d_out);
}

// Round 6
// 151.411 us; speedup vs baseline: 10.4811x; 1.0397x over previous
//
#include <hip/hip_runtime.h>
#include <hip/hip_bf16.h>
#include <math.h>

namespace {

constexpr int Bc = 2;
constexpr int Sc = 2048;
constexpr int Ec = 1024;
constexpr int Hc = 8;
constexpr int Dc = 128;
constexpr int Mc = Bc * Sc; // 4096

typedef unsigned short u16;
typedef u16    u16x8  __attribute__((ext_vector_type(8)));
typedef u16    u16x4  __attribute__((ext_vector_type(4)));
typedef __bf16 bf16x8 __attribute__((ext_vector_type(8)));
typedef float  f32x4  __attribute__((ext_vector_type(4)));

static __device__ inline bf16x8 asbf(u16x8 v) { return __builtin_bit_cast(bf16x8, v); }

static __device__ inline f32x4 mfma16(u16x8 a, u16x8 b, f32x4 c) {
    return __builtin_amdgcn_mfma_f32_16x16x32_bf16(asbf(a), asbf(b), c, 0, 0, 0);
}

static __device__ inline u16 f2bf(float f) {
    unsigned u = __builtin_bit_cast(unsigned, f);
    return (u16)((u + 0x7fffu + ((u >> 16) & 1u)) >> 16);
}
static __device__ inline float bf2f(u16 h) {
    unsigned u = ((unsigned)h) << 16;
    return __builtin_bit_cast(float, u);
}

// Async global->LDS DMA, 16B per lane.  LDS dest wave-uniform; HW writes
// lane l at dest + l*16B.
static __device__ inline void gload16(const u16* g, u16* l) {
    __builtin_amdgcn_global_load_lds(
        (__attribute__((address_space(1))) void*)const_cast<u16*>(g),
        (__attribute__((address_space(3))) void*)l,
        16, 0, 0);
}

// ---------------------------------------------------------------------------
// X f32 -> bf16, flat.
// ---------------------------------------------------------------------------
__global__ __launch_bounds__(256) void convX(const float* __restrict__ in,
                                             u16* __restrict__ out, int n8)
{
    int i = blockIdx.x * 256 + threadIdx.x;
    if (i >= n8) return;
    float4 a = *(const float4*)(in + (size_t)i * 8);
    float4 b = *(const float4*)(in + (size_t)i * 8 + 4);
    u16x8 o;
    o[0] = f2bf(a.x); o[1] = f2bf(a.y); o[2] = f2bf(a.z); o[3] = f2bf(a.w);
    o[4] = f2bf(b.x); o[5] = f2bf(b.y); o[6] = f2bf(b.z); o[7] = f2bf(b.w);
    *(u16x8*)(out + (size_t)i * 8) = o;
}

// ---------------------------------------------------------------------------
// Head-weight transpose+convert: 3 sources [8][1024][128] -> out[z][128][1024].
// ---------------------------------------------------------------------------
__global__ __launch_bounds__(256) void tconvH(const float* __restrict__ p0,
                                              const float* __restrict__ p1,
                                              const float* __restrict__ p2,
                                              u16* __restrict__ out)
{
    const int z = blockIdx.z;
    const float* ip = (z < 8 ? p0 : z < 16 ? p1 : p2) + (size_t)(z & 7) * Ec * Dc;
    u16* op = out + (size_t)z * Dc * Ec;
    __shared__ float tile[32][33];
    const int r0 = blockIdx.x * 32, c0 = blockIdx.y * 32;
    const int ty = threadIdx.x >> 5, tx = threadIdx.x & 31;
#pragma unroll
    for (int i = ty; i < 32; i += 8) tile[i][tx] = ip[(size_t)(r0 + i) * Dc + c0 + tx];
    __syncthreads();
#pragma unroll
    for (int i = ty; i < 32; i += 8) op[(size_t)(c0 + i) * Ec + r0 + tx] = f2bf(tile[tx][i]);
}

// ---------------------------------------------------------------------------
// Square-weight transpose+convert: 2 sources [1024][1024] -> out[z][1024][1024].
// ---------------------------------------------------------------------------
__global__ __launch_bounds__(256) void tconvSq(const float* __restrict__ p0,
                                               const float* __restrict__ p1,
                                               u16* __restrict__ out)
{
    const int z = blockIdx.z;
    const float* ip = z == 0 ? p0 : p1;
    u16* op = out + (size_t)z * Ec * Ec;
    __shared__ float tile[32][33];
    const int r0 = blockIdx.x * 32, c0 = blockIdx.y * 32;
    const int ty = threadIdx.x >> 5, tx = threadIdx.x & 31;
#pragma unroll
    for (int i = ty; i < 32; i += 8) tile[i][tx] = ip[(size_t)(r0 + i) * Ec + c0 + tx];
    __syncthreads();
#pragma unroll
    for (int i = ty; i < 32; i += 8) op[(size_t)(c0 + i) * Ec + r0 + tx] = f2bf(tile[tx][i]);
}

// ---------------------------------------------------------------------------
// xPos trig tables: tabQ[s*64+ip] = (cos*scale, sin*scale), tabK = /scale.
// ---------------------------------------------------------------------------
__global__ __launch_bounds__(256) void trigk(float2* __restrict__ tabQ,
                                             float2* __restrict__ tabK)
{
    int t = blockIdx.x * 256 + threadIdx.x; // 2048*64
    int s = t >> 6, ip = t & 63;
    float sv = (2.f * (float)ip + 51.2f) * (1.f / 179.2f);
    float sc = exp2f(((float)s * (1.f / 512.f)) * log2f(sv));
    float freq = exp2f(-(float)ip * (13.287712379549449f / 64.f));
    float ang = (float)s * freq;
    float sn, cs;
    sincosf(ang, &sn, &cs);
    tabQ[t] = make_float2(cs * sc, sn * sc);
    tabK[t] = make_float2(cs / sc, sn / sc);
}

// ---------------------------------------------------------------------------
// 2-phase GEMM core (T3 minimal): 128x128 tile, BK=32, 4 waves, double-
// buffered linear LDS, global_load_lds staging issued BEFORE compute, one
// vmcnt(0)+s_barrier per K-step (no full drain).
// MFMA called swapped (b, a) -> lane holds C^T frag: row = rl-based,
// cols = hi*4+reg (4 consecutive) -> vectorized epilogue stores.
// acc[rt][ct][reg]: row r0+w*32+rt*16+rl, col n0+ct*16+hi*4+reg.
// ---------------------------------------------------------------------------
#define GCORE_STAGE(lA, lB, k0)                                   \
    do {                                                          \
        gload16(Ag + (k0),                  (lA) + w * 1024);     \
        gload16(Ag + 16 * Ec + (k0),        (lA) + w * 1024 + 512);\
        gload16(Bg + (k0),                  (lB) + w * 1024);     \
        gload16(Bg + 16 * Ec + (k0),        (lB) + w * 1024 + 512);\
    } while (0)

#define GCORE_COMPUTE(lA, lB)                                                 \
    do {                                                                      \
        u16x8 bfr[8];                                                         \
        _Pragma("unroll")                                                     \
        for (int ct = 0; ct < 8; ++ct)                                        \
            bfr[ct] = *(const u16x8*)&(lB)[(ct * 16 + rl) * 32 + hi * 8];     \
        _Pragma("unroll")                                                     \
        for (int rt = 0; rt < 2; ++rt) {                                      \
            u16x8 afr = *(const u16x8*)&(lA)[(w * 32 + rt * 16 + rl) * 32 + hi * 8]; \
            _Pragma("unroll")                                                 \
            for (int ct = 0; ct < 8; ++ct)                                    \
                acc[rt][ct] = mfma16(bfr[ct], afr, acc[rt][ct]);              \
        }                                                                     \
    } while (0)

#define GCORE_SYNC()                                              \
    do {                                                          \
        asm volatile("s_waitcnt vmcnt(0)" ::: "memory");          \
        __builtin_amdgcn_s_barrier();                             \
    } while (0)

// ---------------------------------------------------------------------------
// Fused projection GEMM: Q|K|V|G = X x {Wq,Wk,Wv,Wg}^T.
// blockIdx.y: wsel = y>>3 picks weight/output/epilogue, n0 = (y&7)*128.
// ---------------------------------------------------------------------------
__global__ __launch_bounds__(256) void mgemm4(const u16* __restrict__ A,
                                              const u16* __restrict__ Ball,
                                              u16* __restrict__ Qo,
                                              u16* __restrict__ Ko,
                                              u16* __restrict__ Vo,
                                              u16* __restrict__ Go,
                                              const float2* __restrict__ tabQ,
                                              const float2* __restrict__ tabK)
{
    const int t = threadIdx.x;
    const int lane = t & 63, w = t >> 6;
    const int rl = lane & 15, hi = lane >> 4;
    const int r0 = blockIdx.x * 128;
    const int wsel = blockIdx.y >> 3;
    const int n0 = (blockIdx.y & 7) * 128;
    const u16* Bt = Ball + (size_t)wsel * Ec * Ec;

    __shared__ u16 As0[4096], As1[4096], Bs0[4096], Bs1[4096];

    f32x4 acc[2][8] = {};

    const u16* Ag = A  + (size_t)(r0 + w * 32 + (lane >> 2)) * Ec + (lane & 3) * 8;
    const u16* Bg = Bt + (size_t)(n0 + w * 32 + (lane >> 2)) * Ec + (lane & 3) * 8;

    GCORE_STAGE(As0, Bs0, 0);
    GCORE_SYNC();
    for (int k0 = 0; k0 < Ec; k0 += 64) {
        GCORE_STAGE(As1, Bs1, k0 + 32);
        GCORE_COMPUTE(As0, Bs0);
        GCORE_SYNC();
        if (k0 + 64 < Ec) GCORE_STAGE(As0, Bs0, k0 + 64);
        GCORE_COMPUTE(As1, Bs1);
        GCORE_SYNC();
    }

    u16* Cout = wsel == 0 ? Qo : wsel == 1 ? Ko : wsel == 2 ? Vo : Go;
    const float2* tab = wsel == 0 ? tabQ : tabK;

#pragma unroll
    for (int rt = 0; rt < 2; ++rt) {
        const int row = r0 + w * 32 + rt * 16 + rl;
#pragma unroll
        for (int ct = 0; ct < 8; ++ct) {
            const int col0 = n0 + ct * 16 + hi * 4;
            f32x4 v = acc[rt][ct];
            if (wsel <= 1) { // xPos rotate: pairs (0,1),(2,3) are lane-local
                const size_t tb = (size_t)(row & 2047) * 64 + ((col0 >> 1) & 63);
                const float2 c0 = tab[tb];
                const float2 c1 = tab[tb + 1];
                float e0 = v[0], o0 = v[1], e1 = v[2], o1 = v[3];
                v[0] = e0 * c0.x - o0 * c0.y;
                v[1] = o0 * c0.x + e0 * c0.y;
                v[2] = e1 * c1.x - o1 * c1.y;
                v[3] = o1 * c1.x + e1 * c1.y;
            } else if (wsel == 3) { // silu
#pragma unroll
                for (int r = 0; r < 4; ++r) v[r] = v[r] / (1.f + expf(-v[r]));
            }
            u16x4 pk;
#pragma unroll
            for (int r = 0; r < 4; ++r) pk[r] = f2bf(v[r]);
            *(u16x4*)(Cout + (size_t)row * Ec + col0) = pk;
        }
    }
}

// ---------------------------------------------------------------------------
// Final GEMM: out(f32) = Z x WoT^T.
// ---------------------------------------------------------------------------
__global__ __launch_bounds__(256) void mgemmO(const u16* __restrict__ A,
                                              const u16* __restrict__ Bt,
                                              float* __restrict__ Cout)
{
    const int t = threadIdx.x;
    const int lane = t & 63, w = t >> 6;
    const int rl = lane & 15, hi = lane >> 4;
    const int r0 = blockIdx.x * 128;
    const int n0 = blockIdx.y * 128;

    __shared__ u16 As0[4096], As1[4096], Bs0[4096], Bs1[4096];

    f32x4 acc[2][8] = {};

    const u16* Ag = A  + (size_t)(r0 + w * 32 + (lane >> 2)) * Ec + (lane & 3) * 8;
    const u16* Bg = Bt + (size_t)(n0 + w * 32 + (lane >> 2)) * Ec + (lane & 3) * 8;

    GCORE_STAGE(As0, Bs0, 0);
    GCORE_SYNC();
    for (int k0 = 0; k0 < Ec; k0 += 64) {
        GCORE_STAGE(As1, Bs1, k0 + 32);
        GCORE_COMPUTE(As0, Bs0);
        GCORE_SYNC();
        if (k0 + 64 < Ec) GCORE_STAGE(As0, Bs0, k0 + 64);
        GCORE_COMPUTE(As1, Bs1);
        GCORE_SYNC();
    }

#pragma unroll
    for (int rt = 0; rt < 2; ++rt) {
        const int row = r0 + w * 32 + rt * 16 + rl;
#pragma unroll
        for (int ct = 0; ct < 8; ++ct) {
            const int col0 = n0 + ct * 16 + hi * 4;
            *(f32x4*)(Cout + (size_t)row * Ec + col0) = acc[rt][ct];
        }
    }
}

// ---------------------------------------------------------------------------
// Retention + fused GroupNorm*gate.  Block = (64 Q-rows, one (b,h)), 4 waves.
// Grid 512: bh = id&15 (id%8 = h -> per-XCD K/V L2 residency); a = id>>4,
// rb = a<16 ? 31-a : a-16.
// QK: wave owns m-strip, S^T frag -> decay+mask -> Ss[n][m] (bf16).
// SV swapped mfma -> lane holds Y[n = w*16+rl][d = ct*16+hi*4+reg]:
// GroupNorm reduction = 2 shuffles, vectorized gate/Z access.
// ---------------------------------------------------------------------------
__global__ __launch_bounds__(256) void ret_gn(const u16* __restrict__ Q,
                                              const u16* __restrict__ K,
                                              const u16* __restrict__ V,
                                              const u16* __restrict__ G,
                                              const float* __restrict__ gw,
                                              const float* __restrict__ gbias,
                                              u16* __restrict__ Z)
{
    const int t = threadIdx.x, lane = t & 63, w = t >> 6;
    const int rl = lane & 15, hi = lane >> 4;
    const int id = blockIdx.x;
    const int bh = id & 15;
    const int a  = id >> 4;
    const int rb = (a < 16) ? (31 - a) : (a - 16);
    const int b = bh >> 3, h = bh & 7;

    __shared__ u16 Ks[2][64][136];
    __shared__ u16 Vt[2][128][68]; // V transposed: Vt[buf][d][m]
    __shared__ u16 Ss[64][72];     // S[n][m]

    const float lga = -3.4657359027997265f; // log(1/32)
    const float lgb = -6.2383246250395075f; // log(1/512)
    const float gamma = 1.f - expf(lga + (float)h * (lgb - lga) * (1.f / 7.f));
    const float lg2 = log2f(gamma);

    int c_lo = 0;
    {
        float cut = 9.2103404f / (-logf(gamma)); // weight >= ~1e-4
        int mmin = rb * 64 - (int)cut;
        if (mmin > 0) c_lo = mmin >> 6;
    }

    // per-lane staging geometry
    const int ki = t >> 2,        kq = (t & 3) * 32;  // K: row, 32-elem quarter
    const int vm4 = (t & 15) * 4, vd = (t >> 4) * 8;  // V: 4 rows, 8-d segment
    const u16* Kg0 = K + (size_t)(b * Sc) * Ec + h * Dc;
    const u16* Vg0 = V + (size_t)(b * Sc) * Ec + h * Dc;

    // ---- issue first K/V chunk loads (independent of LDS) ----
    u16x8 kreg[4], vreg[4];
    {
        const u16* Kg = Kg0 + (size_t)(c_lo * 64 + ki) * Ec + kq;
#pragma unroll
        for (int r = 0; r < 4; ++r) kreg[r] = *(const u16x8*)(Kg + r * 8);
        const u16* Vg = Vg0 + (size_t)(c_lo * 64 + vm4) * Ec + vd;
#pragma unroll
        for (int r = 0; r < 4; ++r) vreg[r] = *(const u16x8*)(Vg + (size_t)r * Ec);
    }

    // ---- stage Q through Ks[0]; every wave pulls ALL 64 rows to registers ----
    {
        const int i = t >> 2, q = (t & 3) * 32;
        const u16* Qg = Q + (size_t)(b * Sc + rb * 64 + i) * Ec + h * Dc + q;
        u16x8 v0 = *(const u16x8*)(Qg);
        u16x8 v1 = *(const u16x8*)(Qg + 8);
        u16x8 v2 = *(const u16x8*)(Qg + 16);
        u16x8 v3 = *(const u16x8*)(Qg + 24);
        *(u16x8*)&Ks[0][i][q]      = v0;
        *(u16x8*)&Ks[0][i][q + 8]  = v1;
        *(u16x8*)&Ks[0][i][q + 16] = v2;
        *(u16x8*)&Ks[0][i][q + 24] = v3;
    }
    __syncthreads();
    u16x8 qf[4][4];
#pragma unroll
    for (int nt = 0; nt < 4; ++nt)
#pragma unroll
        for (int ks = 0; ks < 4; ++ks)
            qf[nt][ks] = *(const u16x8*)&Ks[0][nt * 16 + rl][ks * 32 + hi * 8];
    __syncthreads(); // Q frags read before chunk loop overwrites Ks[0]

    // decay: wgt(n,m) = nf[nt] * mf[reg]
    float mf[4];
#pragma unroll
    for (int reg = 0; reg < 4; ++reg)
        mf[reg] = exp2f(-lg2 * (float)(w * 16 + hi * 4 + reg));
    float nf[4];
#pragma unroll
    for (int nt = 0; nt < 4; ++nt)
        nf[nt] = exp2f(lg2 * (float)((rb - c_lo) * 64 + nt * 16 + rl));
    const float ginv64 = exp2f(-lg2 * 64.f);

    f32x4 yacc[8] = {};

    for (int c = c_lo; c <= rb; ++c) {
        const int cur = c & 1;
        // regs -> LDS (double-buffered: no barrier needed before write)
#pragma unroll
        for (int r = 0; r < 4; ++r)
            *(u16x8*)&Ks[cur][ki][kq + r * 8] = kreg[r];
#pragma unroll
        for (int j = 0; j < 8; ++j) {
            u16x4 p;
            p[0] = vreg[0][j]; p[1] = vreg[1][j]; p[2] = vreg[2][j]; p[3] = vreg[3][j];
            *(u16x4*)&Vt[cur][vd + j][vm4] = p;
        }
        __syncthreads();
        if (c < rb) { // prefetch next chunk under compute
            const u16* Kg = Kg0 + (size_t)((c + 1) * 64 + ki) * Ec + kq;
#pragma unroll
            for (int r = 0; r < 4; ++r) kreg[r] = *(const u16x8*)(Kg + r * 8);
            const u16* Vg = Vg0 + (size_t)((c + 1) * 64 + vm4) * Ec + vd;
#pragma unroll
            for (int r = 0; r < 4; ++r) vreg[r] = *(const u16x8*)(Vg + (size_t)r * Ec);
        }

        // QK^T: wave owns m-strip [w*16, w*16+16); S^T frag -> Ss[n][m]
        __builtin_amdgcn_s_setprio(1);
        u16x8 kf[4];
#pragma unroll
        for (int ks = 0; ks < 4; ++ks)
            kf[ks] = *(const u16x8*)&Ks[cur][w * 16 + rl][ks * 32 + hi * 8];
#pragma unroll
        for (int nt = 0; nt < 4; ++nt) {
            f32x4 s = {};
#pragma unroll
            for (int ks = 0; ks < 4; ++ks)
                s = mfma16(kf[ks], qf[nt][ks], s);
            // lane holds S[n = nt*16+rl][m = w*16+hi*4+reg], reg=0..3
            u16x4 pk;
#pragma unroll
            for (int reg = 0; reg < 4; ++reg) {
                float wgt = nf[nt] * mf[reg];
                if (c == rb && (w * 16 + hi * 4 + reg) > (nt * 16 + rl)) wgt = 0.f;
                pk[reg] = f2bf(s[reg] * wgt);
            }
            *(u16x4*)&Ss[nt * 16 + rl][w * 16 + hi * 4] = pk;
        }
        __builtin_amdgcn_s_setprio(0);
        __syncthreads();

        // Y += S V (swapped): lane holds Y[n=w*16+rl][d=ct*16+hi*4+reg]
        u16x8 sf0 = *(const u16x8*)&Ss[w * 16 + rl][hi * 8];
        u16x8 sf1 = *(const u16x8*)&Ss[w * 16 + rl][32 + hi * 8];
        __builtin_amdgcn_s_setprio(1);
#pragma unroll
        for (int ct = 0; ct < 8; ++ct) {
            u16x8 vf0 = *(const u16x8*)&Vt[cur][ct * 16 + rl][hi * 8];
            u16x8 vf1 = *(const u16x8*)&Vt[cur][ct * 16 + rl][32 + hi * 8];
            yacc[ct] = mfma16(vf0, sf0, yacc[ct]);
            yacc[ct] = mfma16(vf1, sf1, yacc[ct]);
        }
        __builtin_amdgcn_s_setprio(0);
#pragma unroll
        for (int nt = 0; nt < 4; ++nt) nf[nt] *= ginv64;
    }

    // ---- fused GroupNorm * gate epilogue (one row per thread) ----
    const int nloc = w * 16 + rl;
    const size_t row = (size_t)(b * Sc + rb * 64 + nloc);
    float s = 0.f, sq = 0.f;
#pragma unroll
    for (int ct = 0; ct < 8; ++ct)
#pragma unroll
        for (int reg = 0; reg < 4; ++reg) {
            float v = yacc[ct][reg];
            s += v; sq += v * v;
        }
    s  += __shfl_xor(s, 16);  sq += __shfl_xor(sq, 16);
    s  += __shfl_xor(s, 32);  sq += __shfl_xor(sq, 32);
    const float mu  = s * (1.f / 128.f);
    const float var = sq * (1.f / 128.f) - mu * mu;
    const float inv = rsqrtf(var + 1e-5f);
#pragma unroll
    for (int ct = 0; ct < 8; ++ct) {
        const int col0 = h * Dc + ct * 16 + hi * 4;
        const f32x4 w4 = *(const f32x4*)(gw + col0);
        const f32x4 b4 = *(const f32x4*)(gbias + col0);
        const u16x4 g4 = *(const u16x4*)(G + row * Ec + col0);
        u16x4 z4;
#pragma unroll
        for (int reg = 0; reg < 4; ++reg)
            z4[reg] = f2bf(((yacc[ct][reg] - mu) * inv * w4[reg] + b4[reg]) * bf2f(g4[reg]));
        *(u16x4*)(Z + row * Ec + col0) = z4;
    }
}

} // anonymous namespace

extern "C" void kernel_launch(void* const* d_in, const int* in_sizes, int n_in,
                              void* d_out, int out_size, void* d_ws, size_t ws_size,
                              hipStream_t stream)
{
    const float* X    = (const float*)d_in[0];
    const float* W_Q  = (const float*)d_in[1];
    const float* W_K  = (const float*)d_in[2];
    const float* W_V  = (const float*)d_in[3];
    const float* W_G  = (const float*)d_in[4];
    const float* W_O  = (const float*)d_in[5];
    const float* gw   = (const float*)d_in[6];
    const float* gb   = (const float*)d_in[7];

    char* ws = (char*)d_ws;
    const size_t NX = (size_t)Mc * Ec;          // 4 Mi elements
    u16*    Xb   = (u16*)ws;                ws += NX * 2;              // 8 MB
    u16*    WqT  = (u16*)ws;                ws += (size_t)Ec * Ec * 2; // 2 MB (x4, contiguous)
    u16*    WkT  = (u16*)ws;                ws += (size_t)Ec * Ec * 2;
    u16*    WvT  = (u16*)ws;                ws += (size_t)Ec * Ec * 2;
    u16*    WgT  = (u16*)ws;                ws += (size_t)Ec * Ec * 2;
    u16*    WoT  = (u16*)ws;                ws += (size_t)Ec * Ec * 2;
    float2* tabQ = (float2*)ws;             ws += (size_t)Sc * 64 * sizeof(float2); // 1 MB
    float2* tabK = (float2*)ws;             ws += (size_t)Sc * 64 * sizeof(float2);
    u16*    Qb   = (u16*)ws;                ws += NX * 2;              // 8 MB
    u16*    Kb   = (u16*)ws;                ws += NX * 2;
    u16*    Vb   = (u16*)ws;                ws += NX * 2;
    u16*    Gb   = (u16*)ws;                ws += NX * 2;
    u16*    Zb   = (u16*)ws;                ws += NX * 2;
    (void)WkT; (void)WvT; (void)WgT;

    dim3 blk(256);
    convX<<<dim3((int)(NX / 8 / 256)), blk, 0, stream>>>(X, Xb, (int)(NX / 8));
    tconvH<<<dim3(32, 4, 24), blk, 0, stream>>>(W_Q, W_K, W_V, WqT);
    tconvSq<<<dim3(32, 32, 2), blk, 0, stream>>>(W_G, W_O, WgT);
    trigk<<<dim3(Sc * 64 / 256), blk, 0, stream>>>(tabQ, tabK);

    mgemm4<<<dim3(Mc / 128, 32), blk, 0, stream>>>(Xb, WqT, Qb, Kb, Vb, Gb, tabQ, tabK);

    ret_gn<<<dim3(512), blk, 0, stream>>>(Qb, Kb, Vb, Gb, gw, gb, Zb);

    mgemmO<<<dim3(Mc / 128, Ec / 128), blk, 0, stream>>>(Zb, WoT, (float*)d_out);
}

// Round 7
// 133.561 us; speedup vs baseline: 11.8819x; 1.1337x over previous
//
#include <hip/hip_runtime.h>
#include <hip/hip_bf16.h>
#include <math.h>

namespace {

constexpr int Bc = 2;
constexpr int Sc = 2048;
constexpr int Ec = 1024;
constexpr int Hc = 8;
constexpr int Dc = 128;
constexpr int Mc = Bc * Sc; // 4096

typedef unsigned short u16;
typedef u16    u16x8  __attribute__((ext_vector_type(8)));
typedef u16    u16x4  __attribute__((ext_vector_type(4)));
typedef __bf16 bf16x8 __attribute__((ext_vector_type(8)));
typedef float  f32x4  __attribute__((ext_vector_type(4)));

static __device__ inline bf16x8 asbf(u16x8 v) { return __builtin_bit_cast(bf16x8, v); }

static __device__ inline f32x4 mfma16(u16x8 a, u16x8 b, f32x4 c) {
    return __builtin_amdgcn_mfma_f32_16x16x32_bf16(asbf(a), asbf(b), c, 0, 0, 0);
}

static __device__ inline u16 f2bf(float f) {
    unsigned u = __builtin_bit_cast(unsigned, f);
    return (u16)((u + 0x7fffu + ((u >> 16) & 1u)) >> 16);
}
static __device__ inline float bf2f(u16 h) {
    unsigned u = ((unsigned)h) << 16;
    return __builtin_bit_cast(float, u);
}

// Async global->LDS DMA, 16B per lane.  LDS dest wave-uniform; HW writes
// lane l at dest + l*16B.
static __device__ inline void gload16(const u16* g, u16* l) {
    __builtin_amdgcn_global_load_lds(
        (__attribute__((address_space(1))) void*)const_cast<u16*>(g),
        (__attribute__((address_space(3))) void*)l,
        16, 0, 0);
}

// ---------------------------------------------------------------------------
// X f32 -> bf16, flat.
// ---------------------------------------------------------------------------
__global__ __launch_bounds__(256) void convX(const float* __restrict__ in,
                                             u16* __restrict__ out, int n8)
{
    int i = blockIdx.x * 256 + threadIdx.x;
    if (i >= n8) return;
    float4 a = *(const float4*)(in + (size_t)i * 8);
    float4 b = *(const float4*)(in + (size_t)i * 8 + 4);
    u16x8 o;
    o[0] = f2bf(a.x); o[1] = f2bf(a.y); o[2] = f2bf(a.z); o[3] = f2bf(a.w);
    o[4] = f2bf(b.x); o[5] = f2bf(b.y); o[6] = f2bf(b.z); o[7] = f2bf(b.w);
    *(u16x8*)(out + (size_t)i * 8) = o;
}

// ---------------------------------------------------------------------------
// Head-weight transpose+convert: 3 sources [8][1024][128] -> out[z][128][1024].
// ---------------------------------------------------------------------------
__global__ __launch_bounds__(256) void tconvH(const float* __restrict__ p0,
                                              const float* __restrict__ p1,
                                              const float* __restrict__ p2,
                                              u16* __restrict__ out)
{
    const int z = blockIdx.z;
    const float* ip = (z < 8 ? p0 : z < 16 ? p1 : p2) + (size_t)(z & 7) * Ec * Dc;
    u16* op = out + (size_t)z * Dc * Ec;
    __shared__ float tile[32][33];
    const int r0 = blockIdx.x * 32, c0 = blockIdx.y * 32;
    const int ty = threadIdx.x >> 5, tx = threadIdx.x & 31;
#pragma unroll
    for (int i = ty; i < 32; i += 8) tile[i][tx] = ip[(size_t)(r0 + i) * Dc + c0 + tx];
    __syncthreads();
#pragma unroll
    for (int i = ty; i < 32; i += 8) op[(size_t)(c0 + i) * Ec + r0 + tx] = f2bf(tile[tx][i]);
}

// ---------------------------------------------------------------------------
// Square-weight transpose+convert: 2 sources [1024][1024] -> out[z][1024][1024].
// ---------------------------------------------------------------------------
__global__ __launch_bounds__(256) void tconvSq(const float* __restrict__ p0,
                                               const float* __restrict__ p1,
                                               u16* __restrict__ out)
{
    const int z = blockIdx.z;
    const float* ip = z == 0 ? p0 : p1;
    u16* op = out + (size_t)z * Ec * Ec;
    __shared__ float tile[32][33];
    const int r0 = blockIdx.x * 32, c0 = blockIdx.y * 32;
    const int ty = threadIdx.x >> 5, tx = threadIdx.x & 31;
#pragma unroll
    for (int i = ty; i < 32; i += 8) tile[i][tx] = ip[(size_t)(r0 + i) * Ec + c0 + tx];
    __syncthreads();
#pragma unroll
    for (int i = ty; i < 32; i += 8) op[(size_t)(c0 + i) * Ec + r0 + tx] = f2bf(tile[tx][i]);
}

// ---------------------------------------------------------------------------
// xPos trig tables: tabQ[s*64+ip] = (cos*scale, sin*scale), tabK = /scale.
// ---------------------------------------------------------------------------
__global__ __launch_bounds__(256) void trigk(float2* __restrict__ tabQ,
                                             float2* __restrict__ tabK)
{
    int t = blockIdx.x * 256 + threadIdx.x; // 2048*64
    int s = t >> 6, ip = t & 63;
    float sv = (2.f * (float)ip + 51.2f) * (1.f / 179.2f);
    float sc = exp2f(((float)s * (1.f / 512.f)) * log2f(sv));
    float freq = exp2f(-(float)ip * (13.287712379549449f / 64.f));
    float ang = (float)s * freq;
    float sn, cs;
    sincosf(ang, &sn, &cs);
    tabQ[t] = make_float2(cs * sc, sn * sc);
    tabK[t] = make_float2(cs / sc, sn / sc);
}

// ---------------------------------------------------------------------------
// 256x256 projection GEMM, counted-vmcnt schedule (T3+T4+T2+T5).
// 512 threads = 8 waves (2 x 4); per-wave output 128x64; BK=64.
// LDS: 2 dbuf x (A 256x64 + B 256x64) bf16, linear rows of 128B with
// swizzle colb ^= ((row&7)<<4) applied via pre-swizzled global SOURCE
// (DMA dest stays linear) and XOR'd ds_read addresses (both-sides, G4/#21).
// Per iter: stage tile t+1 (8 gload_lds/wave), s_waitcnt vmcnt(8) (tile t
// landed, t+1 stays in flight across barriers), barrier, 4 quads of
// {4 ds_read A, setprio(1), 16 MFMA, setprio(0)}, barrier.
// blockIdx.y: wsel = y>>2 (Q/K/V/G), n0 = (y&3)*256.
// ---------------------------------------------------------------------------
__global__ __launch_bounds__(512, 2) void mgemm4(const u16* __restrict__ A,
                                                 const u16* __restrict__ Ball,
                                                 u16* __restrict__ Qo,
                                                 u16* __restrict__ Ko,
                                                 u16* __restrict__ Vo,
                                                 u16* __restrict__ Go,
                                                 const float2* __restrict__ tabQ,
                                                 const float2* __restrict__ tabK)
{
    const int t = threadIdx.x, lane = t & 63, wid = t >> 6;
    const int wm = wid >> 2, wn = wid & 3;
    const int rl = lane & 15, hi = lane >> 4;
    const int r0 = blockIdx.x * 256;
    const int wsel = blockIdx.y >> 2;
    const int n0 = (blockIdx.y & 3) * 256;
    const u16* Bt = Ball + (size_t)wsel * Ec * Ec;

    __shared__ u16 lds[2][2][256 * 64]; // [buf][A/B][row*64 + col], 128 KiB

    f32x4 acc[8][4] = {};

    // staging: wave wid stages rows [wid*32, +32) of both tiles (4 issues x 8
    // rows each).  Source col pre-swizzled so linear DMA dest + swizzled read
    // are consistent: lane l carries logical chunk (l&~7) | ((l&7)^((l>>3)&7)).
    const int srow = lane >> 3;                       // 0..7 within 8-row issue
    const int scol = (((lane & 7) ^ srow) << 3);      // elems
    const u16* Asrc = A  + (size_t)(r0 + wid * 32 + srow) * Ec + scol;
    const u16* Bsrc = Bt + (size_t)(n0 + wid * 32 + srow) * Ec + scol;

#define STAGE256(tile, buf)                                                     \
    do {                                                                        \
        const int _k0 = (tile) * 64;                                            \
        _Pragma("unroll")                                                       \
        for (int i = 0; i < 4; ++i) {                                           \
            gload16(Asrc + (size_t)(i * 8) * Ec + _k0,                          \
                    &lds[buf][0][(wid * 32 + i * 8) * 64]);                     \
            gload16(Bsrc + (size_t)(i * 8) * Ec + _k0,                          \
                    &lds[buf][1][(wid * 32 + i * 8) * 64]);                     \
        }                                                                       \
    } while (0)

    STAGE256(0, 0);
    for (int tt = 0; tt < 16; ++tt) {
        const int buf = tt & 1;
        if (tt + 1 < 16) {
            STAGE256(tt + 1, buf ^ 1);
            asm volatile("s_waitcnt vmcnt(8)" ::: "memory"); // tile tt landed
        } else {
            asm volatile("s_waitcnt vmcnt(0)" ::: "memory");
        }
        __builtin_amdgcn_s_barrier();

        // B fragments for this wave's 64-col strip, once per K-tile
        u16x8 breg[4][2];
#pragma unroll
        for (int cf = 0; cf < 4; ++cf)
#pragma unroll
            for (int ks = 0; ks < 2; ++ks) {
                const int row = wn * 64 + cf * 16 + rl;
                breg[cf][ks] = *(const u16x8*)
                    &lds[buf][1][row * 64 + ((ks * 32 + hi * 8) ^ ((rl & 7) << 3))];
            }
#pragma unroll
        for (int q = 0; q < 4; ++q) {
            u16x8 areg[2][2];
#pragma unroll
            for (int rfi = 0; rfi < 2; ++rfi)
#pragma unroll
                for (int ks = 0; ks < 2; ++ks) {
                    const int row = wm * 128 + (q * 2 + rfi) * 16 + rl;
                    areg[rfi][ks] = *(const u16x8*)
                        &lds[buf][0][row * 64 + ((ks * 32 + hi * 8) ^ ((rl & 7) << 3))];
                }
            __builtin_amdgcn_s_setprio(1);
#pragma unroll
            for (int rfi = 0; rfi < 2; ++rfi)
#pragma unroll
                for (int cf = 0; cf < 4; ++cf)
#pragma unroll
                    for (int ks = 0; ks < 2; ++ks)
                        acc[q * 2 + rfi][cf] =
                            mfma16(breg[cf][ks], areg[rfi][ks], acc[q * 2 + rfi][cf]);
            __builtin_amdgcn_s_setprio(0);
        }
        __builtin_amdgcn_s_barrier();
    }
#undef STAGE256

    u16* Cout = wsel == 0 ? Qo : wsel == 1 ? Ko : wsel == 2 ? Vo : Go;
    const float2* tab = wsel == 0 ? tabQ : tabK;

#pragma unroll
    for (int rf = 0; rf < 8; ++rf) {
        const int row = r0 + wm * 128 + rf * 16 + rl;
#pragma unroll
        for (int cf = 0; cf < 4; ++cf) {
            const int col0 = n0 + wn * 64 + cf * 16 + hi * 4;
            f32x4 v = acc[rf][cf];
            if (wsel <= 1) { // xPos rotate: pairs (0,1),(2,3) lane-local
                const size_t tb = (size_t)(row & 2047) * 64 + ((col0 >> 1) & 63);
                const float2 c0 = tab[tb];
                const float2 c1 = tab[tb + 1];
                float e0 = v[0], o0 = v[1], e1 = v[2], o1 = v[3];
                v[0] = e0 * c0.x - o0 * c0.y;
                v[1] = o0 * c0.x + e0 * c0.y;
                v[2] = e1 * c1.x - o1 * c1.y;
                v[3] = o1 * c1.x + e1 * c1.y;
            } else if (wsel == 3) { // silu
#pragma unroll
                for (int r = 0; r < 4; ++r) v[r] = v[r] / (1.f + expf(-v[r]));
            }
            u16x4 pk;
#pragma unroll
            for (int r = 0; r < 4; ++r) pk[r] = f2bf(v[r]);
            *(u16x4*)(Cout + (size_t)row * Ec + col0) = pk;
        }
    }
}

// ---------------------------------------------------------------------------
// 2-phase GEMM core (round-6): 128x128 tile, BK=32, 4 waves — kept for the
// final GEMM (N=1024 -> 256 blocks at 128x128; a 256 tile would underfill).
// ---------------------------------------------------------------------------
#define GCORE_STAGE(lA, lB, k0)                                   \
    do {                                                          \
        gload16(Ag + (k0),                  (lA) + w * 1024);     \
        gload16(Ag + 16 * Ec + (k0),        (lA) + w * 1024 + 512);\
        gload16(Bg + (k0),                  (lB) + w * 1024);     \
        gload16(Bg + 16 * Ec + (k0),        (lB) + w * 1024 + 512);\
    } while (0)

#define GCORE_COMPUTE(lA, lB)                                                 \
    do {                                                                      \
        u16x8 bfr[8];                                                         \
        _Pragma("unroll")                                                     \
        for (int ct = 0; ct < 8; ++ct)                                        \
            bfr[ct] = *(const u16x8*)&(lB)[(ct * 16 + rl) * 32 + hi * 8];     \
        _Pragma("unroll")                                                     \
        for (int rt = 0; rt < 2; ++rt) {                                      \
            u16x8 afr = *(const u16x8*)&(lA)[(w * 32 + rt * 16 + rl) * 32 + hi * 8]; \
            _Pragma("unroll")                                                 \
            for (int ct = 0; ct < 8; ++ct)                                    \
                acc[rt][ct] = mfma16(bfr[ct], afr, acc[rt][ct]);              \
        }                                                                     \
    } while (0)

#define GCORE_SYNC()                                              \
    do {                                                          \
        asm volatile("s_waitcnt vmcnt(0)" ::: "memory");          \
        __builtin_amdgcn_s_barrier();                             \
    } while (0)

// ---------------------------------------------------------------------------
// Final GEMM: out(f32) = Z x WoT^T.
// ---------------------------------------------------------------------------
__global__ __launch_bounds__(256) void mgemmO(const u16* __restrict__ A,
                                              const u16* __restrict__ Bt,
                                              float* __restrict__ Cout)
{
    const int t = threadIdx.x;
    const int lane = t & 63, w = t >> 6;
    const int rl = lane & 15, hi = lane >> 4;
    const int r0 = blockIdx.x * 128;
    const int n0 = blockIdx.y * 128;

    __shared__ u16 As0[4096], As1[4096], Bs0[4096], Bs1[4096];

    f32x4 acc[2][8] = {};

    const u16* Ag = A  + (size_t)(r0 + w * 32 + (lane >> 2)) * Ec + (lane & 3) * 8;
    const u16* Bg = Bt + (size_t)(n0 + w * 32 + (lane >> 2)) * Ec + (lane & 3) * 8;

    GCORE_STAGE(As0, Bs0, 0);
    GCORE_SYNC();
    for (int k0 = 0; k0 < Ec; k0 += 64) {
        GCORE_STAGE(As1, Bs1, k0 + 32);
        GCORE_COMPUTE(As0, Bs0);
        GCORE_SYNC();
        if (k0 + 64 < Ec) GCORE_STAGE(As0, Bs0, k0 + 64);
        GCORE_COMPUTE(As1, Bs1);
        GCORE_SYNC();
    }

#pragma unroll
    for (int rt = 0; rt < 2; ++rt) {
        const int row = r0 + w * 32 + rt * 16 + rl;
#pragma unroll
        for (int ct = 0; ct < 8; ++ct) {
            const int col0 = n0 + ct * 16 + hi * 4;
            *(f32x4*)(Cout + (size_t)row * Ec + col0) = acc[rt][ct];
        }
    }
}

// ---------------------------------------------------------------------------
// Retention + fused GroupNorm*gate.  Block = (64 Q-rows, one (b,h)), 4 waves.
// Grid 512: bh = id&15 (id%8 = h -> per-XCD K/V L2 residency); a = id>>4,
// rb = a<16 ? 31-a : a-16.
// QK: wave owns m-strip, S^T frag -> decay+mask -> Ss[n][m] (bf16).
// SV swapped mfma -> lane holds Y[n = w*16+rl][d = ct*16+hi*4+reg]:
// GroupNorm reduction = 2 shuffles, vectorized gate/Z access.
// ---------------------------------------------------------------------------
__global__ __launch_bounds__(256) void ret_gn(const u16* __restrict__ Q,
                                              const u16* __restrict__ K,
                                              const u16* __restrict__ V,
                                              const u16* __restrict__ G,
                                              const float* __restrict__ gw,
                                              const float* __restrict__ gbias,
                                              u16* __restrict__ Z)
{
    const int t = threadIdx.x, lane = t & 63, w = t >> 6;
    const int rl = lane & 15, hi = lane >> 4;
    const int id = blockIdx.x;
    const int bh = id & 15;
    const int a  = id >> 4;
    const int rb = (a < 16) ? (31 - a) : (a - 16);
    const int b = bh >> 3, h = bh & 7;

    __shared__ u16 Ks[2][64][136];
    __shared__ u16 Vt[2][128][68]; // V transposed: Vt[buf][d][m]
    __shared__ u16 Ss[64][72];     // S[n][m]

    const float lga = -3.4657359027997265f; // log(1/32)
    const float lgb = -6.2383246250395075f; // log(1/512)
    const float gamma = 1.f - expf(lga + (float)h * (lgb - lga) * (1.f / 7.f));
    const float lg2 = log2f(gamma);

    int c_lo = 0;
    {
        float cut = 9.2103404f / (-logf(gamma)); // weight >= ~1e-4
        int mmin = rb * 64 - (int)cut;
        if (mmin > 0) c_lo = mmin >> 6;
    }

    // per-lane staging geometry
    const int ki = t >> 2,        kq = (t & 3) * 32;  // K: row, 32-elem quarter
    const int vm4 = (t & 15) * 4, vd = (t >> 4) * 8;  // V: 4 rows, 8-d segment
    const u16* Kg0 = K + (size_t)(b * Sc) * Ec + h * Dc;
    const u16* Vg0 = V + (size_t)(b * Sc) * Ec + h * Dc;

    // ---- issue first K/V chunk loads (independent of LDS) ----
    u16x8 kreg[4], vreg[4];
    {
        const u16* Kg = Kg0 + (size_t)(c_lo * 64 + ki) * Ec + kq;
#pragma unroll
        for (int r = 0; r < 4; ++r) kreg[r] = *(const u16x8*)(Kg + r * 8);
        const u16* Vg = Vg0 + (size_t)(c_lo * 64 + vm4) * Ec + vd;
#pragma unroll
        for (int r = 0; r < 4; ++r) vreg[r] = *(const u16x8*)(Vg + (size_t)r * Ec);
    }

    // ---- stage Q through Ks[0]; every wave pulls ALL 64 rows to registers ----
    {
        const int i = t >> 2, q = (t & 3) * 32;
        const u16* Qg = Q + (size_t)(b * Sc + rb * 64 + i) * Ec + h * Dc + q;
        u16x8 v0 = *(const u16x8*)(Qg);
        u16x8 v1 = *(const u16x8*)(Qg + 8);
        u16x8 v2 = *(const u16x8*)(Qg + 16);
        u16x8 v3 = *(const u16x8*)(Qg + 24);
        *(u16x8*)&Ks[0][i][q]      = v0;
        *(u16x8*)&Ks[0][i][q + 8]  = v1;
        *(u16x8*)&Ks[0][i][q + 16] = v2;
        *(u16x8*)&Ks[0][i][q + 24] = v3;
    }
    __syncthreads();
    u16x8 qf[4][4];
#pragma unroll
    for (int nt = 0; nt < 4; ++nt)
#pragma unroll
        for (int ks = 0; ks < 4; ++ks)
            qf[nt][ks] = *(const u16x8*)&Ks[0][nt * 16 + rl][ks * 32 + hi * 8];
    __syncthreads(); // Q frags read before chunk loop overwrites Ks[0]

    // decay: wgt(n,m) = nf[nt] * mf[reg]
    float mf[4];
#pragma unroll
    for (int reg = 0; reg < 4; ++reg)
        mf[reg] = exp2f(-lg2 * (float)(w * 16 + hi * 4 + reg));
    float nf[4];
#pragma unroll
    for (int nt = 0; nt < 4; ++nt)
        nf[nt] = exp2f(lg2 * (float)((rb - c_lo) * 64 + nt * 16 + rl));
    const float ginv64 = exp2f(-lg2 * 64.f);

    f32x4 yacc[8] = {};

    for (int c = c_lo; c <= rb; ++c) {
        const int cur = c & 1;
        // regs -> LDS (double-buffered: no barrier needed before write)
#pragma unroll
        for (int r = 0; r < 4; ++r)
            *(u16x8*)&Ks[cur][ki][kq + r * 8] = kreg[r];
#pragma unroll
        for (int j = 0; j < 8; ++j) {
            u16x4 p;
            p[0] = vreg[0][j]; p[1] = vreg[1][j]; p[2] = vreg[2][j]; p[3] = vreg[3][j];
            *(u16x4*)&Vt[cur][vd + j][vm4] = p;
        }
        __syncthreads();
        if (c < rb) { // prefetch next chunk under compute
            const u16* Kg = Kg0 + (size_t)((c + 1) * 64 + ki) * Ec + kq;
#pragma unroll
            for (int r = 0; r < 4; ++r) kreg[r] = *(const u16x8*)(Kg + r * 8);
            const u16* Vg = Vg0 + (size_t)((c + 1) * 64 + vm4) * Ec + vd;
#pragma unroll
            for (int r = 0; r < 4; ++r) vreg[r] = *(const u16x8*)(Vg + (size_t)r * Ec);
        }

        // QK^T: wave owns m-strip [w*16, w*16+16); S^T frag -> Ss[n][m]
        __builtin_amdgcn_s_setprio(1);
        u16x8 kf[4];
#pragma unroll
        for (int ks = 0; ks < 4; ++ks)
            kf[ks] = *(const u16x8*)&Ks[cur][w * 16 + rl][ks * 32 + hi * 8];
#pragma unroll
        for (int nt = 0; nt < 4; ++nt) {
            f32x4 s = {};
#pragma unroll
            for (int ks = 0; ks < 4; ++ks)
                s = mfma16(kf[ks], qf[nt][ks], s);
            // lane holds S[n = nt*16+rl][m = w*16+hi*4+reg], reg=0..3
            u16x4 pk;
#pragma unroll
            for (int reg = 0; reg < 4; ++reg) {
                float wgt = nf[nt] * mf[reg];
                if (c == rb && (w * 16 + hi * 4 + reg) > (nt * 16 + rl)) wgt = 0.f;
                pk[reg] = f2bf(s[reg] * wgt);
            }
            *(u16x4*)&Ss[nt * 16 + rl][w * 16 + hi * 4] = pk;
        }
        __builtin_amdgcn_s_setprio(0);
        __syncthreads();

        // Y += S V (swapped): lane holds Y[n=w*16+rl][d=ct*16+hi*4+reg]
        u16x8 sf0 = *(const u16x8*)&Ss[w * 16 + rl][hi * 8];
        u16x8 sf1 = *(const u16x8*)&Ss[w * 16 + rl][32 + hi * 8];
        __builtin_amdgcn_s_setprio(1);
#pragma unroll
        for (int ct = 0; ct < 8; ++ct) {
            u16x8 vf0 = *(const u16x8*)&Vt[cur][ct * 16 + rl][hi * 8];
            u16x8 vf1 = *(const u16x8*)&Vt[cur][ct * 16 + rl][32 + hi * 8];
            yacc[ct] = mfma16(vf0, sf0, yacc[ct]);
            yacc[ct] = mfma16(vf1, sf1, yacc[ct]);
        }
        __builtin_amdgcn_s_setprio(0);
#pragma unroll
        for (int nt = 0; nt < 4; ++nt) nf[nt] *= ginv64;
    }

    // ---- fused GroupNorm * gate epilogue (one row per thread) ----
    const int nloc = w * 16 + rl;
    const size_t row = (size_t)(b * Sc + rb * 64 + nloc);
    float s = 0.f, sq = 0.f;
#pragma unroll
    for (int ct = 0; ct < 8; ++ct)
#pragma unroll
        for (int reg = 0; reg < 4; ++reg) {
            float v = yacc[ct][reg];
            s += v; sq += v * v;
        }
    s  += __shfl_xor(s, 16);  sq += __shfl_xor(sq, 16);
    s  += __shfl_xor(s, 32);  sq += __shfl_xor(sq, 32);
    const float mu  = s * (1.f / 128.f);
    const float var = sq * (1.f / 128.f) - mu * mu;
    const float inv = rsqrtf(var + 1e-5f);
#pragma unroll
    for (int ct = 0; ct < 8; ++ct) {
        const int col0 = h * Dc + ct * 16 + hi * 4;
        const f32x4 w4 = *(const f32x4*)(gw + col0);
        const f32x4 b4 = *(const f32x4*)(gbias + col0);
        const u16x4 g4 = *(const u16x4*)(G + row * Ec + col0);
        u16x4 z4;
#pragma unroll
        for (int reg = 0; reg < 4; ++reg)
            z4[reg] = f2bf(((yacc[ct][reg] - mu) * inv * w4[reg] + b4[reg]) * bf2f(g4[reg]));
        *(u16x4*)(Z + row * Ec + col0) = z4;
    }
}

} // anonymous namespace

extern "C" void kernel_launch(void* const* d_in, const int* in_sizes, int n_in,
                              void* d_out, int out_size, void* d_ws, size_t ws_size,
                              hipStream_t stream)
{
    const float* X    = (const float*)d_in[0];
    const float* W_Q  = (const float*)d_in[1];
    const float* W_K  = (const float*)d_in[2];
    const float* W_V  = (const float*)d_in[3];
    const float* W_G  = (const float*)d_in[4];
    const float* W_O  = (const float*)d_in[5];
    const float* gw   = (const float*)d_in[6];
    const float* gb   = (const float*)d_in[7];

    char* ws = (char*)d_ws;
    const size_t NX = (size_t)Mc * Ec;          // 4 Mi elements
    u16*    Xb   = (u16*)ws;                ws += NX * 2;              // 8 MB
    u16*    WqT  = (u16*)ws;                ws += (size_t)Ec * Ec * 2; // 2 MB (x4, contiguous)
    u16*    WkT  = (u16*)ws;                ws += (size_t)Ec * Ec * 2;
    u16*    WvT  = (u16*)ws;                ws += (size_t)Ec * Ec * 2;
    u16*    WgT  = (u16*)ws;                ws += (size_t)Ec * Ec * 2;
    u16*    WoT  = (u16*)ws;                ws += (size_t)Ec * Ec * 2;
    float2* tabQ = (float2*)ws;             ws += (size_t)Sc * 64 * sizeof(float2); // 1 MB
    float2* tabK = (float2*)ws;             ws += (size_t)Sc * 64 * sizeof(float2);
    u16*    Qb   = (u16*)ws;                ws += NX * 2;              // 8 MB
    u16*    Kb   = (u16*)ws;                ws += NX * 2;
    u16*    Vb   = (u16*)ws;                ws += NX * 2;
    u16*    Gb   = (u16*)ws;                ws += NX * 2;
    u16*    Zb   = (u16*)ws;                ws += NX * 2;
    (void)WkT; (void)WvT; (void)WgT;

    dim3 blk(256);
    convX<<<dim3((int)(NX / 8 / 256)), blk, 0, stream>>>(X, Xb, (int)(NX / 8));
    tconvH<<<dim3(32, 4, 24), blk, 0, stream>>>(W_Q, W_K, W_V, WqT);
    tconvSq<<<dim3(32, 32, 2), blk, 0, stream>>>(W_G, W_O, WgT);
    trigk<<<dim3(Sc * 64 / 256), blk, 0, stream>>>(tabQ, tabK);

    mgemm4<<<dim3(Mc / 256, 16), dim3(512), 0, stream>>>(Xb, WqT, Qb, Kb, Vb, Gb, tabQ, tabK);

    ret_gn<<<dim3(512), blk, 0, stream>>>(Qb, Kb, Vb, Gb, gw, gb, Zb);

    mgemmO<<<dim3(Mc / 128, Ec / 128), blk, 0, stream>>>(Zb, WoT, (float*)d_out);
}